// Round 2
// baseline (14655.237 us; speedup 1.0000x reference)
//
#include <hip/hip_runtime.h>
#include <hip/hip_bf16.h>
#include <cstddef>

typedef __hip_bfloat16 bf16;

// ---------------- problem constants ----------------
#define D_MODEL 1048
#define P_DIM   1048
#define NLAYER  3
#define BSZ     4
#define LSEQ    4096
#define BL      (BSZ*LSEQ)                 // 16384 rows
#define BLD     ((size_t)BL*D_MODEL)       // 17,170,432 elements
#define PD      ((size_t)P_DIM*D_MODEL)

// ---------------- load/store helpers (fp32 math everywhere) ----------------
__device__ __forceinline__ float ldf(const float* p, size_t i) { return p[i]; }
__device__ __forceinline__ float ldf(const bf16*  p, size_t i) { return __bfloat162float(p[i]); }
__device__ __forceinline__ void  stf(float* p, size_t i, float v) { p[i] = v; }
__device__ __forceinline__ void  stf(bf16*  p, size_t i, float v) { p[i] = __float2bfloat16(v); }

// ---------------- GEMM: C[m,n] = beta*C[m,n] + alpha*sum_k A[m,k]*W[n,k] ----
#define BMt 64
#define BNt 64
#define BKt 16

template <typename TA, typename TW, typename TC>
__global__ __launch_bounds__(256) void gemm_nt(
    const TA* __restrict__ A, const TW* __restrict__ W,
    TC* __restrict__ C, int M, int N, int K, float alpha, float beta)
{
    __shared__ __align__(16) float As[BKt][BMt+4];
    __shared__ __align__(16) float Ws[BKt][BNt+4];
    const int tid = threadIdx.x;
    const int tx = tid & 15;        // n-group
    const int ty = tid >> 4;        // m-group
    const int m0 = blockIdx.y * BMt;
    const int n0 = blockIdx.x * BNt;
    float acc[4][4] = {};
    for (int k0 = 0; k0 < K; k0 += BKt) {
#pragma unroll
        for (int i = 0; i < 4; ++i) {
            int idx = i*256 + tid;
            int r = idx >> 4, c = idx & 15;
            int kk = k0 + c;
            As[c][r] = (kk < K) ? ldf(A, (size_t)(m0 + r)*K + kk) : 0.f;
            int nr = n0 + r;
            Ws[c][r] = (kk < K && nr < N) ? ldf(W, (size_t)nr*K + kk) : 0.f;
        }
        __syncthreads();
#pragma unroll
        for (int k = 0; k < BKt; ++k) {
            float a4[4], w4[4];
#pragma unroll
            for (int i = 0; i < 4; ++i) a4[i] = As[k][ty*4+i];
#pragma unroll
            for (int j = 0; j < 4; ++j) w4[j] = Ws[k][tx*4+j];
#pragma unroll
            for (int i = 0; i < 4; ++i)
#pragma unroll
                for (int j = 0; j < 4; ++j)
                    acc[i][j] = fmaf(a4[i], w4[j], acc[i][j]);
        }
        __syncthreads();
    }
#pragma unroll
    for (int i = 0; i < 4; ++i) {
        int m = m0 + ty*4 + i;
#pragma unroll
        for (int j = 0; j < 4; ++j) {
            int n = n0 + tx*4 + j;
            if (n < N) {
                size_t o = (size_t)m*N + n;
                float prev = (beta != 0.f) ? beta*ldf(C, o) : 0.f;
                stf(C, o, prev + alpha*acc[i][j]);
            }
        }
    }
}

// ---------------- helpers ----------------
__device__ __forceinline__ float gelu_f(float x) {
    return 0.5f * x * (1.f + erff(x * 0.70710678118654752f));
}

__device__ __forceinline__ float2 block_reduce2(float a, float b) {
    for (int off = 32; off; off >>= 1) {
        a += __shfl_down(a, off, 64);
        b += __shfl_down(b, off, 64);
    }
    __shared__ float sa[4], sb[4];
    int lane = threadIdx.x & 63, wv = threadIdx.x >> 6;
    if (lane == 0) { sa[wv] = a; sb[wv] = b; }
    __syncthreads();
    if (threadIdx.x == 0) {
        sa[0] = sa[0]+sa[1]+sa[2]+sa[3];
        sb[0] = sb[0]+sb[1]+sb[2]+sb[3];
    }
    __syncthreads();
    return make_float2(sa[0], sb[0]);
}

// ---------------- encode: h[bl,d] = x[bl]*ew[d] + eb[d] ----------------
__global__ __launch_bounds__(256) void encode_k(
    const float* __restrict__ x, const float* __restrict__ ew,
    const float* __restrict__ eb, float* __restrict__ h)
{
    size_t i = (size_t)blockIdx.x*256 + threadIdx.x;
    if (i >= BLD) return;
    int d = (int)(i % D_MODEL);
    size_t bl = i / D_MODEL;
    h[i] = x[bl]*ew[d] + eb[d];
}

// ---------------- layernorm over last dim (row per block) ----------------
template <typename TI, typename TO>
__global__ __launch_bounds__(256) void ln_k(
    const TI* __restrict__ x, const float* __restrict__ w,
    const float* __restrict__ b, TO* __restrict__ y)
{
    const size_t row = blockIdx.x;
    const TI* xr = x + row * D_MODEL;
    float v[5];
    float s = 0.f, ss = 0.f;
    int i = 0;
    for (int d = threadIdx.x; d < D_MODEL; d += 256, ++i) {
        float t = ldf(xr, d);
        v[i] = t; s += t; ss += t*t;
    }
    float2 r = block_reduce2(s, ss);
    float mu  = r.x * (1.f/D_MODEL);
    float var = r.y * (1.f/D_MODEL) - mu*mu;
    float inv = rsqrtf(var + 1e-5f);
    TO* yr = y + row * D_MODEL;
    i = 0;
    for (int d = threadIdx.x; d < D_MODEL; d += 256, ++i)
        stf(yr, d, (v[i]-mu)*inv*w[d] + b[d]);
}

// ---------------- per-layer SSM precompute ----------------
// Abar = exp(Lam*step); coef = (Abar-1)/Lam; Bbar = coef * (B_re + i B_im)
__global__ __launch_bounds__(256) void prep_k(
    const float* __restrict__ lam_re, const float* __restrict__ lam_im,
    const float* __restrict__ log_step,
    const float* __restrict__ B_re, const float* __restrict__ B_im,
    bf16* __restrict__ bbar_re, bf16* __restrict__ bbar_im,
    float* __restrict__ abar)
{
    size_t idx = (size_t)blockIdx.x*256 + threadIdx.x;
    if (idx >= PD) return;
    int p = (int)(idx / D_MODEL);
    int d = (int)(idx - (size_t)p*D_MODEL);
    float lr = lam_re[p], li = lam_im[p];
    float st = expf(log_step[p]);
    float er = expf(lr*st);
    float ar = er * cosf(li*st);
    float ai = er * sinf(li*st);
    if (d == 0) { abar[p] = ar; abar[P_DIM + p] = ai; }
    float den = lr*lr + li*li;
    float xr = ar - 1.f, xi = ai;
    float cr = (xr*lr + xi*li) / den;
    float ci = (xi*lr - xr*li) / den;
    float br = B_re[idx], bi = B_im[idx];
    bbar_re[idx] = __float2bfloat16(cr*br - ci*bi);
    bbar_im[idx] = __float2bfloat16(cr*bi + ci*br);
}

// ---------------- sequential scan: x_l = Abar*x_{l-1} + Bu_l (complex) ------
// fp32 state in registers; bf16 in/out buffers (in-place)
__global__ __launch_bounds__(256) void scan_k(
    bf16* __restrict__ xr_buf, bf16* __restrict__ xi_buf,
    const float* __restrict__ abar)
{
    int idx = blockIdx.x*256 + threadIdx.x;
    if (idx >= BSZ*P_DIM) return;
    int b = idx / P_DIM, p = idx - b*P_DIM;
    float ar = abar[p], ai = abar[P_DIM + p];
    size_t base = (size_t)b * LSEQ * P_DIM + p;
    float xre = 0.f, xim = 0.f;
    for (int l = 0; l < LSEQ; ++l) {
        size_t o = base + (size_t)l * P_DIM;
        float br = __bfloat162float(xr_buf[o]);
        float bi = __bfloat162float(xi_buf[o]);
        float nr = fmaf(ar, xre, fmaf(-ai, xim, br));
        float ni = fmaf(ar, xim, fmaf( ai, xre, bi));
        xre = nr; xim = ni;
        xr_buf[o] = __float2bfloat16(xre);
        xi_buf[o] = __float2bfloat16(xim);
    }
}

// ---------------- s-epilogue: z2 = gelu(s + Dvec[d]*fx) + fx (in-place s) ---
__global__ __launch_bounds__(256) void sepi_k(
    bf16* __restrict__ s, const bf16* __restrict__ fx,
    const float* __restrict__ dv)
{
    size_t i = (size_t)blockIdx.x*256 + threadIdx.x;
    if (i >= BLD) return;
    int d = (int)(i % D_MODEL);
    float f = __bfloat162float(fx[i]);
    float t = __bfloat162float(s[i]) + dv[d]*f;
    s[i] = __float2bfloat16(gelu_f(t) + f);
}

// ---------------- GEGLU: a = a * gelu(g) ----------------
__global__ __launch_bounds__(256) void geglu_k(
    bf16* __restrict__ a, const bf16* __restrict__ g)
{
    size_t i = (size_t)blockIdx.x*256 + threadIdx.x;
    if (i >= BLD) return;
    a[i] = __float2bfloat16(__bfloat162float(a[i]) * gelu_f(__bfloat162float(g[i])));
}

// ---------------- residual: h += dec + fy ----------------
__global__ __launch_bounds__(256) void resid_k(
    float* __restrict__ h, const bf16* __restrict__ dec,
    const bf16* __restrict__ fy)
{
    size_t i = (size_t)blockIdx.x*256 + threadIdx.x;
    if (i >= BLD) return;
    h[i] += __bfloat162float(dec[i]) + __bfloat162float(fy[i]);
}

// ---------------- head ----------------
__global__ void head_init_k(float* out, const float* hb)
{
    if (threadIdx.x < BSZ) out[threadIdx.x] = hb[0];
}

__global__ __launch_bounds__(256) void head_k(
    const float* __restrict__ h, const float* __restrict__ hw,
    float* __restrict__ out)
{
    int b = blockIdx.x;
    int chunk = blockIdx.y;  // 64 chunks x 64 l-positions
    const float* hb = h + ((size_t)b*LSEQ + (size_t)chunk*64)*D_MODEL;
    float s = 0.f;
    for (int l = 0; l < 64; ++l) {
        const float* hr = hb + (size_t)l*D_MODEL;
        for (int d = threadIdx.x; d < D_MODEL; d += 256)
            s += hr[d]*hw[d];
    }
    for (int off = 32; off; off >>= 1) s += __shfl_down(s, off, 64);
    __shared__ float sm[4];
    int lane = threadIdx.x & 63, wv = threadIdx.x >> 6;
    if (lane == 0) sm[wv] = s;
    __syncthreads();
    if (threadIdx.x == 0)
        atomicAdd(out + b, (sm[0]+sm[1]+sm[2]+sm[3]) * (1.f/LSEQ));
}

// ---------------- launch ----------------
extern "C" void kernel_launch(void* const* d_in, const int* in_sizes, int n_in,
                              void* d_out, int out_size, void* d_ws, size_t ws_size,
                              hipStream_t stream)
{
    const float* x          = (const float*)d_in[0];
    const float* enc_w      = (const float*)d_in[1];
    const float* enc_b      = (const float*)d_in[2];
    const float* norm_w     = (const float*)d_in[3];
    const float* norm_b     = (const float*)d_in[4];
    const float* attn_w     = (const float*)d_in[5];
    const float* attn_b     = (const float*)d_in[6];
    const float* ff_w       = (const float*)d_in[7];
    const float* ff_b       = (const float*)d_in[8];
    const float* lam_re     = (const float*)d_in[9];
    const float* lam_im     = (const float*)d_in[10];
    const float* log_step   = (const float*)d_in[11];
    const float* B_re       = (const float*)d_in[12];
    const float* B_im       = (const float*)d_in[13];
    const float* C_re       = (const float*)d_in[14];
    const float* C_im       = (const float*)d_in[15];
    const float* Dvec       = (const float*)d_in[16];
    const float* Wenc       = (const float*)d_in[17];
    const float* Wdec       = (const float*)d_in[18];
    const float* head_w     = (const float*)d_in[19];
    const float* head_b     = (const float*)d_in[20];
    float* out = (float*)d_out;

    // ---- workspace layout (bf16 intermediates): ~210 MB total ----
    float* h   = (float*)d_ws;           // BLD fp32       (68.7 MB)
    bf16*  b1  = (bf16*)(h + BLD);       // BLD bf16       (34.3 MB)
    bf16*  b2  = b1 + BLD;
    bf16*  b3  = b2 + BLD;
    bf16*  b4  = b3 + BLD;
    bf16*  bbr = b4 + BLD;               // PD bf16        (2.2 MB)
    bf16*  bbi = bbr + PD;
    float* abar = (float*)(bbi + PD);    // 2*P fp32

    const int EW_BLOCKS = (int)((BLD + 255)/256);
    dim3 gemm_grid((D_MODEL + BNt - 1)/BNt, BL/BMt);   // (17, 256)

    encode_k<<<EW_BLOCKS, 256, 0, stream>>>(x, enc_w, enc_b, h);

    for (int i = 0; i < NLAYER; ++i) {
        prep_k<<<(int)((PD + 255)/256), 256, 0, stream>>>(
            lam_re + i*P_DIM, lam_im + i*P_DIM, log_step + i*P_DIM,
            B_re + i*PD, B_im + i*PD, bbr, bbi, abar);

        // prenorm + inner norm
        ln_k<<<BL, 256, 0, stream>>>(h,  norm_w + i*D_MODEL, norm_b + i*D_MODEL, b1);
        ln_k<<<BL, 256, 0, stream>>>(b1, attn_w + i*D_MODEL, attn_b + i*D_MODEL, b2);

        // Bu = fx @ Bbar^T  (re, im)
        gemm_nt<<<gemm_grid, 256, 0, stream>>>(b2, bbr, b1, BL, P_DIM, D_MODEL, 1.f, 0.f);
        gemm_nt<<<gemm_grid, 256, 0, stream>>>(b2, bbi, b3, BL, P_DIM, D_MODEL, 1.f, 0.f);

        // associative scan along L (in-place)
        scan_k<<<(BSZ*P_DIM + 255)/256, 256, 0, stream>>>(b1, b3, abar);

        // s = xs_re@C_re^T - xs_im@C_im^T
        gemm_nt<<<gemm_grid, 256, 0, stream>>>(b1, C_re + i*PD, b4, BL, D_MODEL, P_DIM,  1.f, 0.f);
        gemm_nt<<<gemm_grid, 256, 0, stream>>>(b3, C_im + i*PD, b4, BL, D_MODEL, P_DIM, -1.f, 1.f);

        // z2 = gelu(s + Dvec*fx) + fx
        sepi_k<<<EW_BLOCKS, 256, 0, stream>>>(b4, b2, Dvec + i*D_MODEL);

        // fy = LN(z2)
        ln_k<<<BL, 256, 0, stream>>>(b4, ff_w + i*D_MODEL, ff_b + i*D_MODEL, b1);

        // GEGLU MLP
        const float* WencA = Wenc + (size_t)i*2*PD;            // rows [0,D)
        const float* WencG = WencA + PD;                       // rows [D,2D)
        gemm_nt<<<gemm_grid, 256, 0, stream>>>(b1, WencA, b2, BL, D_MODEL, D_MODEL, 1.f, 0.f);
        gemm_nt<<<gemm_grid, 256, 0, stream>>>(b1, WencG, b3, BL, D_MODEL, D_MODEL, 1.f, 0.f);
        geglu_k<<<EW_BLOCKS, 256, 0, stream>>>(b2, b3);
        gemm_nt<<<gemm_grid, 256, 0, stream>>>(b2, Wdec + i*PD, b4, BL, D_MODEL, D_MODEL, 1.f, 0.f);

        // h += dec + fy
        resid_k<<<EW_BLOCKS, 256, 0, stream>>>(h, b4, b1);
    }

    // head: out[b] = mean_l sum_d h*hw + head_b
    head_init_k<<<1, 64, 0, stream>>>(out, head_b);
    head_k<<<dim3(BSZ, 64), 256, 0, stream>>>(h, head_w, out);
}

// Round 3
// 3683.563 us; speedup vs baseline: 3.9785x; 3.9785x over previous
//
#include <hip/hip_runtime.h>
#include <hip/hip_bf16.h>
#include <cstddef>

typedef __hip_bfloat16 bf16;

// ---------------- problem constants ----------------
#define D_MODEL 1048
#define P_DIM   1048
#define NLAYER  3
#define BSZ     4
#define LSEQ    4096
#define BL      (BSZ*LSEQ)                 // 16384 rows
#define BLD     ((size_t)BL*D_MODEL)       // unpadded elements
#define KP      1056                       // padded K / row stride (mult of 32)
#define NP      1152                       // padded N for weights (mult of 128)
#define BLA     ((size_t)BL*KP)            // padded activation elements
#define NPKP    ((size_t)NP*KP)            // padded weight elements

// ---------------- MFMA GEMM: C[m,n] = sum_pairs sum_k A[m,k]*W[n,k] --------
// A: [BL][KP] bf16 (zero-padded cols), W: [NP][KP] bf16 (zero-padded), NT form.
// C: [BL][KP] bf16; stores zeros into pad cols [N, KP).
typedef __attribute__((ext_vector_type(8))) short short8;
typedef __attribute__((ext_vector_type(4))) float f32x4;

#define TM 128
#define TN 128
#define TK 32

template <int NPAIR>
__global__ __launch_bounds__(256) void gemm_mfma(
    const bf16* __restrict__ A0, const bf16* __restrict__ W0,
    const bf16* __restrict__ A1, const bf16* __restrict__ W1,
    bf16* __restrict__ C, int N)
{
    __shared__ short As[TM*TK];
    __shared__ short Ws[TN*TK];
    const int tid  = threadIdx.x;
    const int m0   = blockIdx.x * TM;     // 128 m-tiles
    const int n0   = blockIdx.y * TN;     // 9 n-tiles
    const int wave = tid >> 6, lane = tid & 63;
    const int wm = (wave >> 1) * 64, wn = (wave & 1) * 64;
    const int row_in = lane & 15, quad = lane >> 4;

    f32x4 acc[4][4] = {};

    for (int pair = 0; pair < NPAIR; ++pair) {
        const bf16* A = pair ? A1 : A0;
        const bf16* W = pair ? W1 : W0;
        for (int k0 = 0; k0 < KP; k0 += TK) {
            // stage A/W tiles: 8KB each, 16B per lane per call, 2 calls per tile
#pragma unroll
            for (int c = 0; c < 2; ++c) {
                int chunk = tid + 256*c;          // 0..511
                int r = chunk >> 2;               // tile row
                int col = (chunk & 3) * 8;        // element col (16B)
                __builtin_amdgcn_global_load_lds(
                    (const __attribute__((address_space(1))) void*)(A + (size_t)(m0 + r)*KP + k0 + col),
                    (__attribute__((address_space(3))) void*)(As + chunk*8), 16, 0, 0);
                __builtin_amdgcn_global_load_lds(
                    (const __attribute__((address_space(1))) void*)(W + (size_t)(n0 + r)*KP + k0 + col),
                    (__attribute__((address_space(3))) void*)(Ws + chunk*8), 16, 0, 0);
            }
            __syncthreads();
            short8 a[4], b[4];
#pragma unroll
            for (int i = 0; i < 4; ++i) {
                a[i] = *(const short8*)&As[(wm + i*16 + row_in)*TK + quad*8];
                b[i] = *(const short8*)&Ws[(wn + i*16 + row_in)*TK + quad*8];
            }
#pragma unroll
            for (int i = 0; i < 4; ++i)
#pragma unroll
                for (int j = 0; j < 4; ++j)
                    acc[i][j] = __builtin_amdgcn_mfma_f32_16x16x32_bf16(a[i], b[j], acc[i][j], 0, 0, 0);
            __syncthreads();
        }
    }

    // epilogue: C/D layout col=lane&15, row=quad*4+reg (m89/m91-verified)
#pragma unroll
    for (int i = 0; i < 4; ++i) {
#pragma unroll
        for (int j = 0; j < 4; ++j) {
            int n = n0 + wn + j*16 + row_in;
#pragma unroll
            for (int r = 0; r < 4; ++r) {
                int m = m0 + wm + i*16 + quad*4 + r;
                if (n < N)        C[(size_t)m*KP + n] = __float2bfloat16(acc[i][j][r]);
                else if (n < KP)  C[(size_t)m*KP + n] = __float2bfloat16(0.f);
            }
        }
    }
}

// ---------------- weight fp32 -> padded bf16 [NP][KP] ----------------
__global__ __launch_bounds__(256) void convw_k(
    const float* __restrict__ src, bf16* __restrict__ dst,
    int N, int K, float scale)
{
    size_t i = (size_t)blockIdx.x*256 + threadIdx.x;
    if (i >= NPKP) return;
    int n = (int)(i / KP), k = (int)(i - (size_t)n*KP);
    float v = (n < N && k < K) ? scale*src[(size_t)n*K + k] : 0.f;
    dst[i] = __float2bfloat16(v);
}

// ---------------- helpers ----------------
__device__ __forceinline__ float gelu_f(float x) {
    return 0.5f * x * (1.f + erff(x * 0.70710678118654752f));
}

__device__ __forceinline__ float ldf(const float* p, size_t i) { return p[i]; }
__device__ __forceinline__ float ldf(const bf16*  p, size_t i) { return __bfloat162float(p[i]); }

__device__ __forceinline__ float2 block_reduce2(float a, float b) {
    for (int off = 32; off; off >>= 1) {
        a += __shfl_down(a, off, 64);
        b += __shfl_down(b, off, 64);
    }
    __shared__ float sa[4], sb[4];
    int lane = threadIdx.x & 63, wv = threadIdx.x >> 6;
    if (lane == 0) { sa[wv] = a; sb[wv] = b; }
    __syncthreads();
    if (threadIdx.x == 0) {
        sa[0] = sa[0]+sa[1]+sa[2]+sa[3];
        sb[0] = sb[0]+sb[1]+sb[2]+sb[3];
    }
    __syncthreads();
    return make_float2(sa[0], sb[0]);
}

// ---------------- encode: h[bl,d] = x[bl]*ew[d] + eb[d] (unpadded fp32) ----
__global__ __launch_bounds__(256) void encode_k(
    const float* __restrict__ x, const float* __restrict__ ew,
    const float* __restrict__ eb, float* __restrict__ h)
{
    size_t i = (size_t)blockIdx.x*256 + threadIdx.x;
    if (i >= BLD) return;
    int d = (int)(i % D_MODEL);
    size_t bl = i / D_MODEL;
    h[i] = x[bl]*ew[d] + eb[d];
}

// ---------------- layernorm: in stride variable, out [row][KP] bf16 --------
template <typename TI>
__global__ __launch_bounds__(256) void ln_k(
    const TI* __restrict__ x, const float* __restrict__ w,
    const float* __restrict__ b, bf16* __restrict__ y, int in_stride)
{
    const size_t row = blockIdx.x;
    const TI* xr = x + row * (size_t)in_stride;
    float v[5];
    float s = 0.f, ss = 0.f;
    int i = 0;
    for (int d = threadIdx.x; d < KP; d += 256, ++i) {
        float t = (d < D_MODEL) ? ldf(xr, d) : 0.f;
        v[i] = t; s += t; ss += t*t;
    }
    float2 r = block_reduce2(s, ss);
    float mu  = r.x * (1.f/D_MODEL);
    float var = r.y * (1.f/D_MODEL) - mu*mu;
    float inv = rsqrtf(var + 1e-5f);
    bf16* yr = y + row * KP;
    i = 0;
    for (int d = threadIdx.x; d < KP; d += 256, ++i) {
        float o = (d < D_MODEL) ? (v[i]-mu)*inv*w[d] + b[d] : 0.f;
        yr[d] = __float2bfloat16(o);
    }
}

// ---------------- per-layer SSM precompute (padded Bbar) ----------------
__global__ __launch_bounds__(256) void prep_k(
    const float* __restrict__ lam_re, const float* __restrict__ lam_im,
    const float* __restrict__ log_step,
    const float* __restrict__ B_re, const float* __restrict__ B_im,
    bf16* __restrict__ bbar_re, bf16* __restrict__ bbar_im,
    float* __restrict__ abar)
{
    size_t idx = (size_t)blockIdx.x*256 + threadIdx.x;
    if (idx >= NPKP) return;
    int p = (int)(idx / KP);
    int d = (int)(idx - (size_t)p*KP);
    if (p >= P_DIM || d >= D_MODEL) {
        bbar_re[idx] = __float2bfloat16(0.f);
        bbar_im[idx] = __float2bfloat16(0.f);
        return;
    }
    float lr = lam_re[p], li = lam_im[p];
    float st = expf(log_step[p]);
    float er = expf(lr*st);
    float ar = er * cosf(li*st);
    float ai = er * sinf(li*st);
    if (d == 0) { abar[p] = ar; abar[P_DIM + p] = ai; }
    float den = lr*lr + li*li;
    float xr = ar - 1.f, xi = ai;
    float cr = (xr*lr + xi*li) / den;
    float ci = (xi*lr - xr*li) / den;
    float br = B_re[(size_t)p*D_MODEL + d], bi = B_im[(size_t)p*D_MODEL + d];
    bbar_re[idx] = __float2bfloat16(cr*br - ci*bi);
    bbar_im[idx] = __float2bfloat16(cr*bi + ci*br);
}

// ---------------- sequential scan (padded stride) ----------------
__global__ __launch_bounds__(256) void scan_k(
    bf16* __restrict__ xr_buf, bf16* __restrict__ xi_buf,
    const float* __restrict__ abar)
{
    int idx = blockIdx.x*256 + threadIdx.x;
    if (idx >= BSZ*P_DIM) return;
    int b = idx / P_DIM, p = idx - b*P_DIM;
    float ar = abar[p], ai = abar[P_DIM + p];
    size_t base = (size_t)b * LSEQ * KP + p;
    float xre = 0.f, xim = 0.f;
    for (int l = 0; l < LSEQ; ++l) {
        size_t o = base + (size_t)l * KP;
        float br = __bfloat162float(xr_buf[o]);
        float bi = __bfloat162float(xi_buf[o]);
        float nr = fmaf(ar, xre, fmaf(-ai, xim, br));
        float ni = fmaf(ar, xim, fmaf( ai, xre, bi));
        xre = nr; xim = ni;
        xr_buf[o] = __float2bfloat16(xre);
        xi_buf[o] = __float2bfloat16(xim);
    }
}

// ---------------- s-epilogue: z2 = gelu(s + Dvec[d]*fx) + fx ----------------
__global__ __launch_bounds__(256) void sepi_k(
    bf16* __restrict__ s, const bf16* __restrict__ fx,
    const float* __restrict__ dv)
{
    size_t i = (size_t)blockIdx.x*256 + threadIdx.x;
    if (i >= BLA) return;
    int d = (int)(i % KP);
    if (d >= D_MODEL) { s[i] = __float2bfloat16(0.f); return; }
    float f = __bfloat162float(fx[i]);
    float t = __bfloat162float(s[i]) + dv[d]*f;
    s[i] = __float2bfloat16(gelu_f(t) + f);
}

// ---------------- GEGLU: a = a * gelu(g) (pads stay 0) ----------------
__global__ __launch_bounds__(256) void geglu_k(
    bf16* __restrict__ a, const bf16* __restrict__ g)
{
    size_t i = (size_t)blockIdx.x*256 + threadIdx.x;
    if (i >= BLA) return;
    a[i] = __float2bfloat16(__bfloat162float(a[i]) * gelu_f(__bfloat162float(g[i])));
}

// ---------------- residual: h += dec + fy (padded -> unpadded) -------------
__global__ __launch_bounds__(256) void resid_k(
    float* __restrict__ h, const bf16* __restrict__ dec,
    const bf16* __restrict__ fy)
{
    size_t i = (size_t)blockIdx.x*256 + threadIdx.x;
    if (i >= BLD) return;
    size_t bl = i / D_MODEL;
    int d = (int)(i - bl*D_MODEL);
    size_t o = bl*KP + d;
    h[i] += __bfloat162float(dec[o]) + __bfloat162float(fy[o]);
}

// ---------------- head ----------------
__global__ void head_init_k(float* out, const float* hb)
{
    if (threadIdx.x < BSZ) out[threadIdx.x] = hb[0];
}

__global__ __launch_bounds__(256) void head_k(
    const float* __restrict__ h, const float* __restrict__ hw,
    float* __restrict__ out)
{
    int b = blockIdx.x;
    int chunk = blockIdx.y;
    const float* hb = h + ((size_t)b*LSEQ + (size_t)chunk*64)*D_MODEL;
    float s = 0.f;
    for (int l = 0; l < 64; ++l) {
        const float* hr = hb + (size_t)l*D_MODEL;
        for (int d = threadIdx.x; d < D_MODEL; d += 256)
            s += hr[d]*hw[d];
    }
    for (int off = 32; off; off >>= 1) s += __shfl_down(s, off, 64);
    __shared__ float sm[4];
    int lane = threadIdx.x & 63, wv = threadIdx.x >> 6;
    if (lane == 0) sm[wv] = s;
    __syncthreads();
    if (threadIdx.x == 0)
        atomicAdd(out + b, (sm[0]+sm[1]+sm[2]+sm[3]) * (1.f/LSEQ));
}

// ---------------- launch ----------------
extern "C" void kernel_launch(void* const* d_in, const int* in_sizes, int n_in,
                              void* d_out, int out_size, void* d_ws, size_t ws_size,
                              hipStream_t stream)
{
    const float* x          = (const float*)d_in[0];
    const float* enc_w      = (const float*)d_in[1];
    const float* enc_b      = (const float*)d_in[2];
    const float* norm_w     = (const float*)d_in[3];
    const float* norm_b     = (const float*)d_in[4];
    const float* attn_w     = (const float*)d_in[5];
    const float* attn_b     = (const float*)d_in[6];
    const float* ff_w       = (const float*)d_in[7];
    const float* ff_b       = (const float*)d_in[8];
    const float* lam_re     = (const float*)d_in[9];
    const float* lam_im     = (const float*)d_in[10];
    const float* log_step   = (const float*)d_in[11];
    const float* B_re       = (const float*)d_in[12];
    const float* B_im       = (const float*)d_in[13];
    const float* C_re       = (const float*)d_in[14];
    const float* C_im       = (const float*)d_in[15];
    const float* Dvec       = (const float*)d_in[16];
    const float* Wenc       = (const float*)d_in[17];
    const float* Wdec       = (const float*)d_in[18];
    const float* head_w     = (const float*)d_in[19];
    const float* head_b     = (const float*)d_in[20];
    float* out = (float*)d_out;

    // ---- workspace: 68.7 + 4*34.6 + 7*2.43 MB ~= 224 MB ----
    float* h    = (float*)d_ws;            // BLD fp32
    bf16*  b1   = (bf16*)(h + BLD);        // BLA bf16 each
    bf16*  b2   = b1 + BLA;
    bf16*  b3   = b2 + BLA;
    bf16*  b4   = b3 + BLA;
    bf16*  wbr  = b4 + BLA;                // 7 padded weight bufs
    bf16*  wbi  = wbr + NPKP;
    bf16*  wcr  = wbi + NPKP;
    bf16*  wci  = wcr + NPKP;              // holds -C_im
    bf16*  wea  = wci + NPKP;
    bf16*  weg  = wea + NPKP;
    bf16*  wd   = weg + NPKP;
    float* abar = (float*)(wd + NPKP);     // 2*P fp32

    const int EW_U = (int)((BLD + 255)/256);   // unpadded elementwise
    const int EW_P = (int)((BLA + 255)/256);   // padded elementwise
    const int CV   = (int)((NPKP + 255)/256);  // weight conversion
    const size_t pd = (size_t)P_DIM*D_MODEL;
    dim3 gg(BL/TM, NP/TN);                     // (128, 9)

    encode_k<<<EW_U, 256, 0, stream>>>(x, enc_w, enc_b, h);

    for (int i = 0; i < NLAYER; ++i) {
        prep_k<<<CV, 256, 0, stream>>>(
            lam_re + i*P_DIM, lam_im + i*P_DIM, log_step + i*P_DIM,
            B_re + i*pd, B_im + i*pd, wbr, wbi, abar);
        convw_k<<<CV, 256, 0, stream>>>(C_re + i*pd, wcr, D_MODEL, P_DIM,  1.f);
        convw_k<<<CV, 256, 0, stream>>>(C_im + i*pd, wci, D_MODEL, P_DIM, -1.f);
        const float* WencA = Wenc + (size_t)i*2*pd;
        const float* WencG = WencA + pd;
        convw_k<<<CV, 256, 0, stream>>>(WencA, wea, D_MODEL, D_MODEL, 1.f);
        convw_k<<<CV, 256, 0, stream>>>(WencG, weg, D_MODEL, D_MODEL, 1.f);
        convw_k<<<CV, 256, 0, stream>>>(Wdec + i*pd, wd, D_MODEL, D_MODEL, 1.f);

        // prenorm + inner norm
        ln_k<<<BL, 256, 0, stream>>>(h,  norm_w + i*D_MODEL, norm_b + i*D_MODEL, b1, D_MODEL);
        ln_k<<<BL, 256, 0, stream>>>(b1, attn_w + i*D_MODEL, attn_b + i*D_MODEL, b2, KP);

        // Bu = fx @ Bbar^T  (re, im)
        gemm_mfma<1><<<gg, 256, 0, stream>>>(b2, wbr, nullptr, nullptr, b1, P_DIM);
        gemm_mfma<1><<<gg, 256, 0, stream>>>(b2, wbi, nullptr, nullptr, b3, P_DIM);

        // associative scan along L (in-place, fp32 state)
        scan_k<<<(BSZ*P_DIM + 255)/256, 256, 0, stream>>>(b1, b3, abar);

        // s = xs_re@C_re^T + xs_im@(-C_im)^T  (dual-accumulate)
        gemm_mfma<2><<<gg, 256, 0, stream>>>(b1, wcr, b3, wci, b4, D_MODEL);

        // z2 = gelu(s + Dvec*fx) + fx
        sepi_k<<<EW_P, 256, 0, stream>>>(b4, b2, Dvec + i*D_MODEL);

        // fy = LN(z2)
        ln_k<<<BL, 256, 0, stream>>>(b4, ff_w + i*D_MODEL, ff_b + i*D_MODEL, b1, KP);

        // GEGLU MLP
        gemm_mfma<1><<<gg, 256, 0, stream>>>(b1, wea, nullptr, nullptr, b2, D_MODEL);
        gemm_mfma<1><<<gg, 256, 0, stream>>>(b1, weg, nullptr, nullptr, b3, D_MODEL);
        geglu_k<<<EW_P, 256, 0, stream>>>(b2, b3);
        gemm_mfma<1><<<gg, 256, 0, stream>>>(b2, wd, nullptr, nullptr, b4, D_MODEL);

        // h += dec + fy
        resid_k<<<EW_U, 256, 0, stream>>>(h, b4, b1);
    }

    head_init_k<<<1, 64, 0, stream>>>(out, head_b);
    head_k<<<dim3(BSZ, 64), 256, 0, stream>>>(h, head_w, out);
}

// Round 4
// 2467.912 us; speedup vs baseline: 5.9383x; 1.4926x over previous
//
#include <hip/hip_runtime.h>
#include <hip/hip_bf16.h>
#include <cstddef>

typedef __hip_bfloat16 bf16;

// ---------------- problem constants ----------------
#define D_MODEL 1048
#define P_DIM   1048
#define NLAYER  3
#define BSZ     4
#define LSEQ    4096
#define BL      (BSZ*LSEQ)                 // 16384 rows
#define BLD     ((size_t)BL*D_MODEL)       // unpadded elements
#define KP      1056                       // padded K / row stride (mult of 32)
#define NP      1152                       // padded N for weights (mult of 128)
#define BLA     ((size_t)BL*KP)            // padded activation elements
#define NPKP    ((size_t)NP*KP)            // padded weight elements

// scan chunking
#define NC      64                         // chunks along L
#define CL      (LSEQ/NC)                  // 64 steps per chunk
#define NSCAN   (BSZ*NC*P_DIM)             // 268,288 scan threads

// ---------------- MFMA GEMM: C[m,n] = sum_pairs sum_k A[m,k]*W[n,k] --------
typedef __attribute__((ext_vector_type(8))) short short8;
typedef __attribute__((ext_vector_type(4))) float f32x4;

#define TM 128
#define TN 128
#define TK 32

template <int NPAIR>
__global__ __launch_bounds__(256) void gemm_mfma(
    const bf16* __restrict__ A0, const bf16* __restrict__ W0,
    const bf16* __restrict__ A1, const bf16* __restrict__ W1,
    bf16* __restrict__ C, int N)
{
    __shared__ short As[TM*TK];
    __shared__ short Ws[TN*TK];
    const int tid  = threadIdx.x;
    const int m0   = blockIdx.x * TM;
    const int n0   = blockIdx.y * TN;
    const int wave = tid >> 6, lane = tid & 63;
    const int wm = (wave >> 1) * 64, wn = (wave & 1) * 64;
    const int row_in = lane & 15, quad = lane >> 4;

    f32x4 acc[4][4] = {};

    for (int pair = 0; pair < NPAIR; ++pair) {
        const bf16* A = pair ? A1 : A0;
        const bf16* W = pair ? W1 : W0;
        for (int k0 = 0; k0 < KP; k0 += TK) {
#pragma unroll
            for (int c = 0; c < 2; ++c) {
                int chunk = tid + 256*c;          // 0..511
                int r = chunk >> 2;
                int col = (chunk & 3) * 8;
                __builtin_amdgcn_global_load_lds(
                    (const __attribute__((address_space(1))) void*)(A + (size_t)(m0 + r)*KP + k0 + col),
                    (__attribute__((address_space(3))) void*)(As + chunk*8), 16, 0, 0);
                __builtin_amdgcn_global_load_lds(
                    (const __attribute__((address_space(1))) void*)(W + (size_t)(n0 + r)*KP + k0 + col),
                    (__attribute__((address_space(3))) void*)(Ws + chunk*8), 16, 0, 0);
            }
            __syncthreads();
            short8 a[4], b[4];
#pragma unroll
            for (int i = 0; i < 4; ++i) {
                a[i] = *(const short8*)&As[(wm + i*16 + row_in)*TK + quad*8];
                b[i] = *(const short8*)&Ws[(wn + i*16 + row_in)*TK + quad*8];
            }
#pragma unroll
            for (int i = 0; i < 4; ++i)
#pragma unroll
                for (int j = 0; j < 4; ++j)
                    acc[i][j] = __builtin_amdgcn_mfma_f32_16x16x32_bf16(a[i], b[j], acc[i][j], 0, 0, 0);
            __syncthreads();
        }
    }

#pragma unroll
    for (int i = 0; i < 4; ++i) {
#pragma unroll
        for (int j = 0; j < 4; ++j) {
            int n = n0 + wn + j*16 + row_in;
#pragma unroll
            for (int r = 0; r < 4; ++r) {
                int m = m0 + wm + i*16 + quad*4 + r;
                if (n < N)        C[(size_t)m*KP + n] = __float2bfloat16(acc[i][j][r]);
                else if (n < KP)  C[(size_t)m*KP + n] = __float2bfloat16(0.f);
            }
        }
    }
}

// ---------------- weight fp32 -> padded bf16 [NP][KP] ----------------
__global__ __launch_bounds__(256) void convw_k(
    const float* __restrict__ src, bf16* __restrict__ dst,
    int N, int K, float scale)
{
    size_t i = (size_t)blockIdx.x*256 + threadIdx.x;
    if (i >= NPKP) return;
    int n = (int)(i / KP), k = (int)(i - (size_t)n*KP);
    float v = (n < N && k < K) ? scale*src[(size_t)n*K + k] : 0.f;
    dst[i] = __float2bfloat16(v);
}

// ---------------- helpers ----------------
__device__ __forceinline__ float gelu_f(float x) {
    return 0.5f * x * (1.f + erff(x * 0.70710678118654752f));
}

__device__ __forceinline__ float ldf(const float* p, size_t i) { return p[i]; }
__device__ __forceinline__ float ldf(const bf16*  p, size_t i) { return __bfloat162float(p[i]); }

__device__ __forceinline__ float2 block_reduce2(float a, float b) {
    for (int off = 32; off; off >>= 1) {
        a += __shfl_down(a, off, 64);
        b += __shfl_down(b, off, 64);
    }
    __shared__ float sa[4], sb[4];
    int lane = threadIdx.x & 63, wv = threadIdx.x >> 6;
    if (lane == 0) { sa[wv] = a; sb[wv] = b; }
    __syncthreads();
    if (threadIdx.x == 0) {
        sa[0] = sa[0]+sa[1]+sa[2]+sa[3];
        sb[0] = sb[0]+sb[1]+sb[2]+sb[3];
    }
    __syncthreads();
    return make_float2(sa[0], sb[0]);
}

// ---------------- encode: h[bl,d] = x[bl]*ew[d] + eb[d] (unpadded fp32) ----
__global__ __launch_bounds__(256) void encode_k(
    const float* __restrict__ x, const float* __restrict__ ew,
    const float* __restrict__ eb, float* __restrict__ h)
{
    size_t i = (size_t)blockIdx.x*256 + threadIdx.x;
    if (i >= BLD) return;
    int d = (int)(i % D_MODEL);
    size_t bl = i / D_MODEL;
    h[i] = x[bl]*ew[d] + eb[d];
}

// ---------------- layernorm: in stride variable, out [row][KP] bf16 --------
template <typename TI>
__global__ __launch_bounds__(256) void ln_k(
    const TI* __restrict__ x, const float* __restrict__ w,
    const float* __restrict__ b, bf16* __restrict__ y, int in_stride)
{
    const size_t row = blockIdx.x;
    const TI* xr = x + row * (size_t)in_stride;
    float v[5];
    float s = 0.f, ss = 0.f;
    int i = 0;
    for (int d = threadIdx.x; d < KP; d += 256, ++i) {
        float t = (d < D_MODEL) ? ldf(xr, d) : 0.f;
        v[i] = t; s += t; ss += t*t;
    }
    float2 r = block_reduce2(s, ss);
    float mu  = r.x * (1.f/D_MODEL);
    float var = r.y * (1.f/D_MODEL) - mu*mu;
    float inv = rsqrtf(var + 1e-5f);
    bf16* yr = y + row * KP;
    i = 0;
    for (int d = threadIdx.x; d < KP; d += 256, ++i) {
        float o = (d < D_MODEL) ? (v[i]-mu)*inv*w[d] + b[d] : 0.f;
        yr[d] = __float2bfloat16(o);
    }
}

// ---------------- per-layer SSM precompute (padded Bbar) ----------------
__global__ __launch_bounds__(256) void prep_k(
    const float* __restrict__ lam_re, const float* __restrict__ lam_im,
    const float* __restrict__ log_step,
    const float* __restrict__ B_re, const float* __restrict__ B_im,
    bf16* __restrict__ bbar_re, bf16* __restrict__ bbar_im,
    float* __restrict__ abar)
{
    size_t idx = (size_t)blockIdx.x*256 + threadIdx.x;
    if (idx >= NPKP) return;
    int p = (int)(idx / KP);
    int d = (int)(idx - (size_t)p*KP);
    if (p >= P_DIM || d >= D_MODEL) {
        bbar_re[idx] = __float2bfloat16(0.f);
        bbar_im[idx] = __float2bfloat16(0.f);
        return;
    }
    float lr = lam_re[p], li = lam_im[p];
    float st = expf(log_step[p]);
    float er = expf(lr*st);
    float ar = er * cosf(li*st);
    float ai = er * sinf(li*st);
    if (d == 0) { abar[p] = ar; abar[P_DIM + p] = ai; }
    float den = lr*lr + li*li;
    float xr = ar - 1.f, xi = ai;
    float cr = (xr*lr + xi*li) / den;
    float ci = (xi*lr - xr*li) / den;
    float br = B_re[(size_t)p*D_MODEL + d], bi = B_im[(size_t)p*D_MODEL + d];
    bbar_re[idx] = __float2bfloat16(cr*br - ci*bi);
    bbar_im[idx] = __float2bfloat16(cr*bi + ci*br);
}

// ---------------- chunked parallel scan ----------------
// idx -> p (fastest), c, b.  u buffers: [b][l][p] stride KP, l = c*CL + i.
// Phase 1: S_c = sum_i a^(CL-1-i) u_i   (recurrence S = a*S + u)
__global__ __launch_bounds__(256) void scan_partial_k(
    const bf16* __restrict__ ur, const bf16* __restrict__ ui,
    const float* __restrict__ abar,
    float* __restrict__ sum_re, float* __restrict__ sum_im)
{
    int idx = blockIdx.x*256 + threadIdx.x;
    if (idx >= NSCAN) return;
    int p = idx % P_DIM;
    int rest = idx / P_DIM;
    int c = rest % NC, b = rest / NC;
    float ar = abar[p], ai = abar[P_DIM + p];
    size_t base = ((size_t)b*LSEQ + (size_t)c*CL)*KP + p;
    float sre = 0.f, sim = 0.f;
    for (int i = 0; i < CL; ++i) {
        size_t o = base + (size_t)i*KP;
        float br = __bfloat162float(ur[o]);
        float bi = __bfloat162float(ui[o]);
        float nr = fmaf(ar, sre, fmaf(-ai, sim, br));
        float ni = fmaf(ar, sim, fmaf( ai, sre, bi));
        sre = nr; sim = ni;
    }
    sum_re[idx] = sre; sum_im[idx] = sim;
}

// Phase 2: carries across chunks: carry_c stored, carry = a^CL*carry + S_c
__global__ __launch_bounds__(256) void scan_carry_k(
    const float* __restrict__ sum_re, const float* __restrict__ sum_im,
    const float* __restrict__ abar,
    float* __restrict__ car_re, float* __restrict__ car_im)
{
    int idx = blockIdx.x*256 + threadIdx.x;
    if (idx >= BSZ*P_DIM) return;
    int p = idx % P_DIM, b = idx / P_DIM;
    float cr = abar[p], ci = abar[P_DIM + p];
#pragma unroll
    for (int s = 0; s < 6; ++s) {       // a^64 by repeated squaring
        float nr = cr*cr - ci*ci;
        float ni = 2.f*cr*ci;
        cr = nr; ci = ni;
    }
    float xre = 0.f, xim = 0.f;
    size_t base = (size_t)b*NC*P_DIM + p;
    for (int c = 0; c < NC; ++c) {
        size_t o = base + (size_t)c*P_DIM;
        car_re[o] = xre; car_im[o] = xim;
        float sre = sum_re[o], sim = sum_im[o];
        float nr = fmaf(cr, xre, fmaf(-ci, xim, sre));
        float ni = fmaf(cr, xim, fmaf( ci, xre, sim));
        xre = nr; xim = ni;
    }
}

// Phase 3: re-run local recurrence seeded with carry; write in-place
__global__ __launch_bounds__(256) void scan_apply_k(
    bf16* __restrict__ ur, bf16* __restrict__ ui,
    const float* __restrict__ abar,
    const float* __restrict__ car_re, const float* __restrict__ car_im)
{
    int idx = blockIdx.x*256 + threadIdx.x;
    if (idx >= NSCAN) return;
    int p = idx % P_DIM;
    int rest = idx / P_DIM;
    int c = rest % NC, b = rest / NC;
    float ar = abar[p], ai = abar[P_DIM + p];
    size_t co = (size_t)b*NC*P_DIM + (size_t)c*P_DIM + p;
    float xre = car_re[co], xim = car_im[co];
    size_t base = ((size_t)b*LSEQ + (size_t)c*CL)*KP + p;
    for (int i = 0; i < CL; ++i) {
        size_t o = base + (size_t)i*KP;
        float br = __bfloat162float(ur[o]);
        float bi = __bfloat162float(ui[o]);
        float nr = fmaf(ar, xre, fmaf(-ai, xim, br));
        float ni = fmaf(ar, xim, fmaf( ai, xre, bi));
        xre = nr; xim = ni;
        ur[o] = __float2bfloat16(xre);
        ui[o] = __float2bfloat16(xim);
    }
}

// ---------------- s-epilogue: z2 = gelu(s + Dvec[d]*fx) + fx ----------------
__global__ __launch_bounds__(256) void sepi_k(
    bf16* __restrict__ s, const bf16* __restrict__ fx,
    const float* __restrict__ dv)
{
    size_t i = (size_t)blockIdx.x*256 + threadIdx.x;
    if (i >= BLA) return;
    int d = (int)(i % KP);
    if (d >= D_MODEL) { s[i] = __float2bfloat16(0.f); return; }
    float f = __bfloat162float(fx[i]);
    float t = __bfloat162float(s[i]) + dv[d]*f;
    s[i] = __float2bfloat16(gelu_f(t) + f);
}

// ---------------- GEGLU: a = a * gelu(g) (pads stay 0) ----------------
__global__ __launch_bounds__(256) void geglu_k(
    bf16* __restrict__ a, const bf16* __restrict__ g)
{
    size_t i = (size_t)blockIdx.x*256 + threadIdx.x;
    if (i >= BLA) return;
    a[i] = __float2bfloat16(__bfloat162float(a[i]) * gelu_f(__bfloat162float(g[i])));
}

// ---------------- residual: h += dec + fy (padded -> unpadded) -------------
__global__ __launch_bounds__(256) void resid_k(
    float* __restrict__ h, const bf16* __restrict__ dec,
    const bf16* __restrict__ fy)
{
    size_t i = (size_t)blockIdx.x*256 + threadIdx.x;
    if (i >= BLD) return;
    size_t bl = i / D_MODEL;
    int d = (int)(i - bl*D_MODEL);
    size_t o = bl*KP + d;
    h[i] += __bfloat162float(dec[o]) + __bfloat162float(fy[o]);
}

// ---------------- head ----------------
__global__ void head_init_k(float* out, const float* hb)
{
    if (threadIdx.x < BSZ) out[threadIdx.x] = hb[0];
}

__global__ __launch_bounds__(256) void head_k(
    const float* __restrict__ h, const float* __restrict__ hw,
    float* __restrict__ out)
{
    int b = blockIdx.x;
    int chunk = blockIdx.y;
    const float* hb = h + ((size_t)b*LSEQ + (size_t)chunk*64)*D_MODEL;
    float s = 0.f;
    for (int l = 0; l < 64; ++l) {
        const float* hr = hb + (size_t)l*D_MODEL;
        for (int d = threadIdx.x; d < D_MODEL; d += 256)
            s += hr[d]*hw[d];
    }
    for (int off = 32; off; off >>= 1) s += __shfl_down(s, off, 64);
    __shared__ float sm[4];
    int lane = threadIdx.x & 63, wv = threadIdx.x >> 6;
    if (lane == 0) sm[wv] = s;
    __syncthreads();
    if (threadIdx.x == 0)
        atomicAdd(out + b, (sm[0]+sm[1]+sm[2]+sm[3]) * (1.f/LSEQ));
}

// ---------------- launch ----------------
extern "C" void kernel_launch(void* const* d_in, const int* in_sizes, int n_in,
                              void* d_out, int out_size, void* d_ws, size_t ws_size,
                              hipStream_t stream)
{
    const float* x          = (const float*)d_in[0];
    const float* enc_w      = (const float*)d_in[1];
    const float* enc_b      = (const float*)d_in[2];
    const float* norm_w     = (const float*)d_in[3];
    const float* norm_b     = (const float*)d_in[4];
    const float* attn_w     = (const float*)d_in[5];
    const float* attn_b     = (const float*)d_in[6];
    const float* ff_w       = (const float*)d_in[7];
    const float* ff_b       = (const float*)d_in[8];
    const float* lam_re     = (const float*)d_in[9];
    const float* lam_im     = (const float*)d_in[10];
    const float* log_step   = (const float*)d_in[11];
    const float* B_re       = (const float*)d_in[12];
    const float* B_im       = (const float*)d_in[13];
    const float* C_re       = (const float*)d_in[14];
    const float* C_im       = (const float*)d_in[15];
    const float* Dvec       = (const float*)d_in[16];
    const float* Wenc       = (const float*)d_in[17];
    const float* Wdec       = (const float*)d_in[18];
    const float* head_w     = (const float*)d_in[19];
    const float* head_b     = (const float*)d_in[20];
    float* out = (float*)d_out;

    // ---- workspace: ~229 MB total ----
    float* h    = (float*)d_ws;            // BLD fp32
    bf16*  b1   = (bf16*)(h + BLD);        // BLA bf16 each
    bf16*  b2   = b1 + BLA;
    bf16*  b3   = b2 + BLA;
    bf16*  b4   = b3 + BLA;
    bf16*  wbr  = b4 + BLA;                // 7 padded weight bufs
    bf16*  wbi  = wbr + NPKP;
    bf16*  wcr  = wbi + NPKP;
    bf16*  wci  = wcr + NPKP;              // holds -C_im
    bf16*  wea  = wci + NPKP;
    bf16*  weg  = wea + NPKP;
    bf16*  wd   = weg + NPKP;
    float* abar = (float*)(wd + NPKP);     // 2*P fp32
    float* sum_re = abar + 2*P_DIM;        // NSCAN fp32 each
    float* sum_im = sum_re + NSCAN;
    float* car_re = sum_im + NSCAN;
    float* car_im = car_re + NSCAN;

    const int EW_U = (int)((BLD + 255)/256);
    const int EW_P = (int)((BLA + 255)/256);
    const int CV   = (int)((NPKP + 255)/256);
    const int SC_G = (NSCAN + 255)/256;
    const size_t pd = (size_t)P_DIM*D_MODEL;
    dim3 gg(BL/TM, NP/TN);                 // (128, 9)

    encode_k<<<EW_U, 256, 0, stream>>>(x, enc_w, enc_b, h);

    for (int i = 0; i < NLAYER; ++i) {
        prep_k<<<CV, 256, 0, stream>>>(
            lam_re + i*P_DIM, lam_im + i*P_DIM, log_step + i*P_DIM,
            B_re + i*pd, B_im + i*pd, wbr, wbi, abar);
        convw_k<<<CV, 256, 0, stream>>>(C_re + i*pd, wcr, D_MODEL, P_DIM,  1.f);
        convw_k<<<CV, 256, 0, stream>>>(C_im + i*pd, wci, D_MODEL, P_DIM, -1.f);
        const float* WencA = Wenc + (size_t)i*2*pd;
        const float* WencG = WencA + pd;
        convw_k<<<CV, 256, 0, stream>>>(WencA, wea, D_MODEL, D_MODEL, 1.f);
        convw_k<<<CV, 256, 0, stream>>>(WencG, weg, D_MODEL, D_MODEL, 1.f);
        convw_k<<<CV, 256, 0, stream>>>(Wdec + i*pd, wd, D_MODEL, D_MODEL, 1.f);

        // prenorm + inner norm
        ln_k<<<BL, 256, 0, stream>>>(h,  norm_w + i*D_MODEL, norm_b + i*D_MODEL, b1, D_MODEL);
        ln_k<<<BL, 256, 0, stream>>>(b1, attn_w + i*D_MODEL, attn_b + i*D_MODEL, b2, KP);

        // Bu = fx @ Bbar^T  (re, im)
        gemm_mfma<1><<<gg, 256, 0, stream>>>(b2, wbr, nullptr, nullptr, b1, P_DIM);
        gemm_mfma<1><<<gg, 256, 0, stream>>>(b2, wbi, nullptr, nullptr, b3, P_DIM);

        // chunked parallel scan along L (in-place on b1/b3)
        scan_partial_k<<<SC_G, 256, 0, stream>>>(b1, b3, abar, sum_re, sum_im);
        scan_carry_k<<<(BSZ*P_DIM + 255)/256, 256, 0, stream>>>(sum_re, sum_im, abar, car_re, car_im);
        scan_apply_k<<<SC_G, 256, 0, stream>>>(b1, b3, abar, car_re, car_im);

        // s = xs_re@C_re^T + xs_im@(-C_im)^T  (dual-accumulate)
        gemm_mfma<2><<<gg, 256, 0, stream>>>(b1, wcr, b3, wci, b4, D_MODEL);

        // z2 = gelu(s + Dvec*fx) + fx
        sepi_k<<<EW_P, 256, 0, stream>>>(b4, b2, Dvec + i*D_MODEL);

        // fy = LN(z2)
        ln_k<<<BL, 256, 0, stream>>>(b4, ff_w + i*D_MODEL, ff_b + i*D_MODEL, b1, KP);

        // GEGLU MLP
        gemm_mfma<1><<<gg, 256, 0, stream>>>(b1, wea, nullptr, nullptr, b2, D_MODEL);
        gemm_mfma<1><<<gg, 256, 0, stream>>>(b1, weg, nullptr, nullptr, b3, D_MODEL);
        geglu_k<<<EW_P, 256, 0, stream>>>(b2, b3);
        gemm_mfma<1><<<gg, 256, 0, stream>>>(b2, wd, nullptr, nullptr, b4, D_MODEL);

        // h += dec + fy
        resid_k<<<EW_U, 256, 0, stream>>>(h, b4, b1);
    }

    head_init_k<<<1, 64, 0, stream>>>(out, head_b);
    head_k<<<dim3(BSZ, 64), 256, 0, stream>>>(h, head_w, out);
}

// Round 5
// 2368.856 us; speedup vs baseline: 6.1866x; 1.0418x over previous
//
#include <hip/hip_runtime.h>
#include <hip/hip_bf16.h>
#include <cstddef>

typedef __hip_bfloat16 bf16;

// ---------------- problem constants ----------------
#define D_MODEL 1048
#define P_DIM   1048
#define NLAYER  3
#define BSZ     4
#define LSEQ    4096
#define BL      (BSZ*LSEQ)                 // 16384 rows
#define BLD     ((size_t)BL*D_MODEL)       // unpadded elements
#define KP      1056                       // padded K / row stride (mult of 32)
#define NP      1152                       // padded N for weights (mult of 128)
#define BLA     ((size_t)BL*KP)            // padded activation elements
#define NPKP    ((size_t)NP*KP)            // padded weight elements

// scan chunking
#define NC      64
#define CL      (LSEQ/NC)                  // 64
#define NSCAN   (BSZ*NC*P_DIM)

typedef __attribute__((ext_vector_type(8))) short short8;
typedef __attribute__((ext_vector_type(4))) float f32x4;

#define TM 128
#define TN 128
#define TK 32

__device__ __forceinline__ float gelu_f(float x) {
    return 0.5f * x * (1.f + erff(x * 0.70710678118654752f));
}

// ---------------- staging helper: one 128x32 bf16 tile via global_load_lds --
__device__ __forceinline__ void stage_tile(
    const bf16* __restrict__ src, int row0, int k0, short* lds, int tid)
{
#pragma unroll
    for (int c = 0; c < 2; ++c) {
        int chunk = tid + 256*c;          // 0..511
        int r = chunk >> 2;
        int col = (chunk & 3) * 8;
        __builtin_amdgcn_global_load_lds(
            (const __attribute__((address_space(1))) void*)(src + (size_t)(row0 + r)*KP + k0 + col),
            (__attribute__((address_space(3))) void*)(lds + chunk*8), 16, 0, 0);
    }
}

// ---------------- dual-output GEMM: acc0 = A@W0^T, acc1 = A@W1^T ------------
// MODE 0: store both (pads zeroed).  MODE 1: O0 = acc0 * gelu(acc1).
template <int MODE>
__global__ __launch_bounds__(256, 2) void gemm2o_k(
    const bf16* __restrict__ A, const bf16* __restrict__ W0,
    const bf16* __restrict__ W1,
    bf16* __restrict__ O0, bf16* __restrict__ O1, int N)
{
    __shared__ short As[TM*TK];
    __shared__ short Ws0[TN*TK];
    __shared__ short Ws1[TN*TK];
    const int tid  = threadIdx.x;
    const int m0   = blockIdx.x * TM;
    const int n0   = blockIdx.y * TN;
    const int wave = tid >> 6, lane = tid & 63;
    const int wm = (wave >> 1) * 64, wn = (wave & 1) * 64;
    const int row_in = lane & 15, quad = lane >> 4;

    f32x4 acc0[4][4] = {};
    f32x4 acc1[4][4] = {};

    for (int k0 = 0; k0 < KP; k0 += TK) {
        stage_tile(A,  m0, k0, As,  tid);
        stage_tile(W0, n0, k0, Ws0, tid);
        stage_tile(W1, n0, k0, Ws1, tid);
        __syncthreads();
        short8 a[4], b0[4], b1[4];
#pragma unroll
        for (int i = 0; i < 4; ++i) {
            a[i]  = *(const short8*)&As [(wm + i*16 + row_in)*TK + quad*8];
            b0[i] = *(const short8*)&Ws0[(wn + i*16 + row_in)*TK + quad*8];
            b1[i] = *(const short8*)&Ws1[(wn + i*16 + row_in)*TK + quad*8];
        }
#pragma unroll
        for (int i = 0; i < 4; ++i)
#pragma unroll
            for (int j = 0; j < 4; ++j) {
                acc0[i][j] = __builtin_amdgcn_mfma_f32_16x16x32_bf16(a[i], b0[j], acc0[i][j], 0, 0, 0);
                acc1[i][j] = __builtin_amdgcn_mfma_f32_16x16x32_bf16(a[i], b1[j], acc1[i][j], 0, 0, 0);
            }
        __syncthreads();
    }

#pragma unroll
    for (int i = 0; i < 4; ++i) {
#pragma unroll
        for (int j = 0; j < 4; ++j) {
            int n = n0 + wn + j*16 + row_in;
#pragma unroll
            for (int r = 0; r < 4; ++r) {
                int m = m0 + wm + i*16 + quad*4 + r;
                size_t o = (size_t)m*KP + n;
                if (MODE == 0) {
                    if (n < N)        { O0[o] = __float2bfloat16(acc0[i][j][r]);
                                        O1[o] = __float2bfloat16(acc1[i][j][r]); }
                    else if (n < KP)  { O0[o] = __float2bfloat16(0.f);
                                        O1[o] = __float2bfloat16(0.f); }
                } else {
                    if (n < N)        O0[o] = __float2bfloat16(acc0[i][j][r] * gelu_f(acc1[i][j][r]));
                    else if (n < KP)  O0[o] = __float2bfloat16(0.f);
                }
            }
        }
    }
}

// ---------------- dual-input GEMM + sepi epilogue ----------------
// acc = A0@W0^T + A1@W1^T;  O = gelu(acc + dv[n]*fx) + fx   (pads zeroed)
__global__ __launch_bounds__(256) void gemmC_k(
    const bf16* __restrict__ A0, const bf16* __restrict__ W0,
    const bf16* __restrict__ A1, const bf16* __restrict__ W1,
    const bf16* __restrict__ fx, const float* __restrict__ dv,
    bf16* __restrict__ O, int N)
{
    __shared__ short As[TM*TK];
    __shared__ short Ws[TN*TK];
    const int tid  = threadIdx.x;
    const int m0   = blockIdx.x * TM;
    const int n0   = blockIdx.y * TN;
    const int wave = tid >> 6, lane = tid & 63;
    const int wm = (wave >> 1) * 64, wn = (wave & 1) * 64;
    const int row_in = lane & 15, quad = lane >> 4;

    f32x4 acc[4][4] = {};

    for (int pair = 0; pair < 2; ++pair) {
        const bf16* A = pair ? A1 : A0;
        const bf16* W = pair ? W1 : W0;
        for (int k0 = 0; k0 < KP; k0 += TK) {
            stage_tile(A, m0, k0, As, tid);
            stage_tile(W, n0, k0, Ws, tid);
            __syncthreads();
            short8 a[4], b[4];
#pragma unroll
            for (int i = 0; i < 4; ++i) {
                a[i] = *(const short8*)&As[(wm + i*16 + row_in)*TK + quad*8];
                b[i] = *(const short8*)&Ws[(wn + i*16 + row_in)*TK + quad*8];
            }
#pragma unroll
            for (int i = 0; i < 4; ++i)
#pragma unroll
                for (int j = 0; j < 4; ++j)
                    acc[i][j] = __builtin_amdgcn_mfma_f32_16x16x32_bf16(a[i], b[j], acc[i][j], 0, 0, 0);
            __syncthreads();
        }
    }

#pragma unroll
    for (int i = 0; i < 4; ++i) {
#pragma unroll
        for (int j = 0; j < 4; ++j) {
            int n = n0 + wn + j*16 + row_in;
#pragma unroll
            for (int r = 0; r < 4; ++r) {
                int m = m0 + wm + i*16 + quad*4 + r;
                size_t o = (size_t)m*KP + n;
                if (n < N) {
                    float f = __bfloat162float(fx[o]);
                    float t = acc[i][j][r] + dv[n]*f;
                    O[o] = __float2bfloat16(gelu_f(t) + f);
                } else if (n < KP) {
                    O[o] = __float2bfloat16(0.f);
                }
            }
        }
    }
}

// ---------------- single GEMM + residual epilogue: h += acc + fy -----------
__global__ __launch_bounds__(256) void gemmD_k(
    const bf16* __restrict__ A, const bf16* __restrict__ W,
    const bf16* __restrict__ fy, float* __restrict__ h, int N)
{
    __shared__ short As[TM*TK];
    __shared__ short Ws[TN*TK];
    const int tid  = threadIdx.x;
    const int m0   = blockIdx.x * TM;
    const int n0   = blockIdx.y * TN;
    const int wave = tid >> 6, lane = tid & 63;
    const int wm = (wave >> 1) * 64, wn = (wave & 1) * 64;
    const int row_in = lane & 15, quad = lane >> 4;

    f32x4 acc[4][4] = {};

    for (int k0 = 0; k0 < KP; k0 += TK) {
        stage_tile(A, m0, k0, As, tid);
        stage_tile(W, n0, k0, Ws, tid);
        __syncthreads();
        short8 a[4], b[4];
#pragma unroll
        for (int i = 0; i < 4; ++i) {
            a[i] = *(const short8*)&As[(wm + i*16 + row_in)*TK + quad*8];
            b[i] = *(const short8*)&Ws[(wn + i*16 + row_in)*TK + quad*8];
        }
#pragma unroll
        for (int i = 0; i < 4; ++i)
#pragma unroll
            for (int j = 0; j < 4; ++j)
                acc[i][j] = __builtin_amdgcn_mfma_f32_16x16x32_bf16(a[i], b[j], acc[i][j], 0, 0, 0);
        __syncthreads();
    }

#pragma unroll
    for (int i = 0; i < 4; ++i) {
#pragma unroll
        for (int j = 0; j < 4; ++j) {
            int n = n0 + wn + j*16 + row_in;
            if (n >= N) continue;
#pragma unroll
            for (int r = 0; r < 4; ++r) {
                int m = m0 + wm + i*16 + quad*4 + r;
                float f = __bfloat162float(fy[(size_t)m*KP + n]);
                h[(size_t)m*D_MODEL + n] += acc[i][j][r] + f;
            }
        }
    }
}

// ---------------- batched weight conversion (5x 1048x1048 fp32 -> bf16) ----
__global__ __launch_bounds__(256) void convw5_k(
    const float* __restrict__ s0, const float* __restrict__ s1,
    const float* __restrict__ s2, const float* __restrict__ s3,
    const float* __restrict__ s4, bf16* __restrict__ dst)
{
    size_t i = (size_t)blockIdx.x*256 + threadIdx.x;
    if (i >= NPKP) return;
    int z = blockIdx.z;
    const float* src = (z == 0) ? s0 : (z == 1) ? s1 : (z == 2) ? s2 : (z == 3) ? s3 : s4;
    float scale = (z == 1) ? -1.f : 1.f;
    int n = (int)(i / KP), k = (int)(i - (size_t)n*KP);
    float v = (n < D_MODEL && k < D_MODEL) ? scale*src[(size_t)n*D_MODEL + k] : 0.f;
    dst[(size_t)z*NPKP + i] = __float2bfloat16(v);
}

// ---------------- reductions ----------------
__device__ __forceinline__ float2 block_reduce2(float a, float b) {
    __syncthreads();   // safe for repeated calls (shared reuse)
    for (int off = 32; off; off >>= 1) {
        a += __shfl_down(a, off, 64);
        b += __shfl_down(b, off, 64);
    }
    __shared__ float sa[4], sb[4];
    int lane = threadIdx.x & 63, wv = threadIdx.x >> 6;
    if (lane == 0) { sa[wv] = a; sb[wv] = b; }
    __syncthreads();
    if (threadIdx.x == 0) {
        sa[0] = sa[0]+sa[1]+sa[2]+sa[3];
        sb[0] = sb[0]+sb[1]+sb[2]+sb[3];
    }
    __syncthreads();
    return make_float2(sa[0], sb[0]);
}

// ---------------- encode ----------------
__global__ __launch_bounds__(256) void encode_k(
    const float* __restrict__ x, const float* __restrict__ ew,
    const float* __restrict__ eb, float* __restrict__ h)
{
    size_t i = (size_t)blockIdx.x*256 + threadIdx.x;
    if (i >= BLD) return;
    int d = (int)(i % D_MODEL);
    size_t bl = i / D_MODEL;
    h[i] = x[bl]*ew[d] + eb[d];
}

// ---------------- fused double layernorm: fx = LN(LN(h,w1,b1),w2,b2) -------
__global__ __launch_bounds__(256) void ln2x_k(
    const float* __restrict__ x,
    const float* __restrict__ w1, const float* __restrict__ bb1,
    const float* __restrict__ w2, const float* __restrict__ bb2,
    bf16* __restrict__ y)
{
    const size_t row = blockIdx.x;
    const float* xr = x + row * D_MODEL;
    float v[5];
    float s = 0.f, ss = 0.f;
    int i = 0;
    for (int d = threadIdx.x; d < KP; d += 256, ++i) {
        float t = (d < D_MODEL) ? xr[d] : 0.f;
        v[i] = t; s += t; ss += t*t;
    }
    float2 r = block_reduce2(s, ss);
    float mu  = r.x * (1.f/D_MODEL);
    float var = r.y * (1.f/D_MODEL) - mu*mu;
    float inv = rsqrtf(var + 1e-5f);
    s = 0.f; ss = 0.f; i = 0;
    for (int d = threadIdx.x; d < KP; d += 256, ++i) {
        float z = (d < D_MODEL) ? (v[i]-mu)*inv*w1[d] + bb1[d] : 0.f;
        v[i] = z; s += z; ss += z*z;
    }
    r = block_reduce2(s, ss);
    mu  = r.x * (1.f/D_MODEL);
    var = r.y * (1.f/D_MODEL) - mu*mu;
    inv = rsqrtf(var + 1e-5f);
    bf16* yr = y + row * KP;
    i = 0;
    for (int d = threadIdx.x; d < KP; d += 256, ++i) {
        float o = (d < D_MODEL) ? (v[i]-mu)*inv*w2[d] + bb2[d] : 0.f;
        yr[d] = __float2bfloat16(o);
    }
}

// ---------------- single layernorm (bf16 in stride KP) ----------------
__global__ __launch_bounds__(256) void ln_k(
    const bf16* __restrict__ x, const float* __restrict__ w,
    const float* __restrict__ b, bf16* __restrict__ y)
{
    const size_t row = blockIdx.x;
    const bf16* xr = x + row * KP;
    float v[5];
    float s = 0.f, ss = 0.f;
    int i = 0;
    for (int d = threadIdx.x; d < KP; d += 256, ++i) {
        float t = (d < D_MODEL) ? __bfloat162float(xr[d]) : 0.f;
        v[i] = t; s += t; ss += t*t;
    }
    float2 r = block_reduce2(s, ss);
    float mu  = r.x * (1.f/D_MODEL);
    float var = r.y * (1.f/D_MODEL) - mu*mu;
    float inv = rsqrtf(var + 1e-5f);
    bf16* yr = y + row * KP;
    i = 0;
    for (int d = threadIdx.x; d < KP; d += 256, ++i) {
        float o = (d < D_MODEL) ? (v[i]-mu)*inv*w[d] + b[d] : 0.f;
        yr[d] = __float2bfloat16(o);
    }
}

// ---------------- per-layer SSM precompute (padded Bbar) ----------------
__global__ __launch_bounds__(256) void prep_k(
    const float* __restrict__ lam_re, const float* __restrict__ lam_im,
    const float* __restrict__ log_step,
    const float* __restrict__ B_re, const float* __restrict__ B_im,
    bf16* __restrict__ bbar_re, bf16* __restrict__ bbar_im,
    float* __restrict__ abar)
{
    size_t idx = (size_t)blockIdx.x*256 + threadIdx.x;
    if (idx >= NPKP) return;
    int p = (int)(idx / KP);
    int d = (int)(idx - (size_t)p*KP);
    if (p >= P_DIM || d >= D_MODEL) {
        bbar_re[idx] = __float2bfloat16(0.f);
        bbar_im[idx] = __float2bfloat16(0.f);
        return;
    }
    float lr = lam_re[p], li = lam_im[p];
    float st = expf(log_step[p]);
    float er = expf(lr*st);
    float ar = er * cosf(li*st);
    float ai = er * sinf(li*st);
    if (d == 0) { abar[p] = ar; abar[P_DIM + p] = ai; }
    float den = lr*lr + li*li;
    float xr = ar - 1.f, xi = ai;
    float cr = (xr*lr + xi*li) / den;
    float ci = (xi*lr - xr*li) / den;
    float br = B_re[(size_t)p*D_MODEL + d], bi = B_im[(size_t)p*D_MODEL + d];
    bbar_re[idx] = __float2bfloat16(cr*br - ci*bi);
    bbar_im[idx] = __float2bfloat16(cr*bi + ci*br);
}

// ---------------- chunked parallel scan ----------------
__global__ __launch_bounds__(256) void scan_partial_k(
    const bf16* __restrict__ ur, const bf16* __restrict__ ui,
    const float* __restrict__ abar,
    float* __restrict__ sum_re, float* __restrict__ sum_im)
{
    int idx = blockIdx.x*256 + threadIdx.x;
    if (idx >= NSCAN) return;
    int p = idx % P_DIM;
    int rest = idx / P_DIM;
    int c = rest % NC, b = rest / NC;
    float ar = abar[p], ai = abar[P_DIM + p];
    size_t base = ((size_t)b*LSEQ + (size_t)c*CL)*KP + p;
    float sre = 0.f, sim = 0.f;
    for (int i = 0; i < CL; ++i) {
        size_t o = base + (size_t)i*KP;
        float br = __bfloat162float(ur[o]);
        float bi = __bfloat162float(ui[o]);
        float nr = fmaf(ar, sre, fmaf(-ai, sim, br));
        float ni = fmaf(ar, sim, fmaf( ai, sre, bi));
        sre = nr; sim = ni;
    }
    sum_re[idx] = sre; sum_im[idx] = sim;
}

__global__ __launch_bounds__(256) void scan_carry_k(
    const float* __restrict__ sum_re, const float* __restrict__ sum_im,
    const float* __restrict__ abar,
    float* __restrict__ car_re, float* __restrict__ car_im)
{
    int idx = blockIdx.x*256 + threadIdx.x;
    if (idx >= BSZ*P_DIM) return;
    int p = idx % P_DIM, b = idx / P_DIM;
    float cr = abar[p], ci = abar[P_DIM + p];
#pragma unroll
    for (int s = 0; s < 6; ++s) {
        float nr = cr*cr - ci*ci;
        float ni = 2.f*cr*ci;
        cr = nr; ci = ni;
    }
    float xre = 0.f, xim = 0.f;
    size_t base = (size_t)b*NC*P_DIM + p;
    for (int c = 0; c < NC; ++c) {
        size_t o = base + (size_t)c*P_DIM;
        car_re[o] = xre; car_im[o] = xim;
        float sre = sum_re[o], sim = sum_im[o];
        float nr = fmaf(cr, xre, fmaf(-ci, xim, sre));
        float ni = fmaf(cr, xim, fmaf( ci, xre, sim));
        xre = nr; xim = ni;
    }
}

__global__ __launch_bounds__(256) void scan_apply_k(
    bf16* __restrict__ ur, bf16* __restrict__ ui,
    const float* __restrict__ abar,
    const float* __restrict__ car_re, const float* __restrict__ car_im)
{
    int idx = blockIdx.x*256 + threadIdx.x;
    if (idx >= NSCAN) return;
    int p = idx % P_DIM;
    int rest = idx / P_DIM;
    int c = rest % NC, b = rest / NC;
    float ar = abar[p], ai = abar[P_DIM + p];
    size_t co = (size_t)b*NC*P_DIM + (size_t)c*P_DIM + p;
    float xre = car_re[co], xim = car_im[co];
    size_t base = ((size_t)b*LSEQ + (size_t)c*CL)*KP + p;
    for (int i = 0; i < CL; ++i) {
        size_t o = base + (size_t)i*KP;
        float br = __bfloat162float(ur[o]);
        float bi = __bfloat162float(ui[o]);
        float nr = fmaf(ar, xre, fmaf(-ai, xim, br));
        float ni = fmaf(ar, xim, fmaf( ai, xre, bi));
        xre = nr; xim = ni;
        ur[o] = __float2bfloat16(xre);
        ui[o] = __float2bfloat16(xim);
    }
}

// ---------------- head ----------------
__global__ void head_init_k(float* out, const float* hb)
{
    if (threadIdx.x < BSZ) out[threadIdx.x] = hb[0];
}

__global__ __launch_bounds__(256) void head_k(
    const float* __restrict__ h, const float* __restrict__ hw,
    float* __restrict__ out)
{
    int b = blockIdx.x;
    int chunk = blockIdx.y;
    const float* hb = h + ((size_t)b*LSEQ + (size_t)chunk*64)*D_MODEL;
    float s = 0.f;
    for (int l = 0; l < 64; ++l) {
        const float* hr = hb + (size_t)l*D_MODEL;
        for (int d = threadIdx.x; d < D_MODEL; d += 256)
            s += hr[d]*hw[d];
    }
    for (int off = 32; off; off >>= 1) s += __shfl_down(s, off, 64);
    __shared__ float sm[4];
    int lane = threadIdx.x & 63, wv = threadIdx.x >> 6;
    if (lane == 0) sm[wv] = s;
    __syncthreads();
    if (threadIdx.x == 0)
        atomicAdd(out + b, (sm[0]+sm[1]+sm[2]+sm[3]) * (1.f/LSEQ));
}

// ---------------- launch ----------------
extern "C" void kernel_launch(void* const* d_in, const int* in_sizes, int n_in,
                              void* d_out, int out_size, void* d_ws, size_t ws_size,
                              hipStream_t stream)
{
    const float* x          = (const float*)d_in[0];
    const float* enc_w      = (const float*)d_in[1];
    const float* enc_b      = (const float*)d_in[2];
    const float* norm_w     = (const float*)d_in[3];
    const float* norm_b     = (const float*)d_in[4];
    const float* attn_w     = (const float*)d_in[5];
    const float* attn_b     = (const float*)d_in[6];
    const float* ff_w       = (const float*)d_in[7];
    const float* ff_b       = (const float*)d_in[8];
    const float* lam_re     = (const float*)d_in[9];
    const float* lam_im     = (const float*)d_in[10];
    const float* log_step   = (const float*)d_in[11];
    const float* B_re       = (const float*)d_in[12];
    const float* B_im       = (const float*)d_in[13];
    const float* C_re       = (const float*)d_in[14];
    const float* C_im       = (const float*)d_in[15];
    const float* Dvec       = (const float*)d_in[16];
    const float* Wenc       = (const float*)d_in[17];
    const float* Wdec       = (const float*)d_in[18];
    const float* head_w     = (const float*)d_in[19];
    const float* head_b     = (const float*)d_in[20];
    float* out = (float*)d_out;

    // ---- workspace (~233 MB) ----
    float* h    = (float*)d_ws;            // BLD fp32
    bf16*  b1   = (bf16*)(h + BLD);        // BLA bf16 each
    bf16*  b2   = b1 + BLA;
    bf16*  b3   = b2 + BLA;
    bf16*  b4   = b3 + BLA;
    bf16*  wbr  = b4 + BLA;                // Bbar re/im
    bf16*  wbi  = wbr + NPKP;
    bf16*  w5   = wbi + NPKP;              // wcr,wci(-),wea,weg,wd contiguous
    bf16*  wcr  = w5;
    bf16*  wci  = w5 + NPKP;
    bf16*  wea  = w5 + 2*NPKP;
    bf16*  weg  = w5 + 3*NPKP;
    bf16*  wd   = w5 + 4*NPKP;
    float* abar = (float*)(w5 + 5*NPKP);   // 2*P fp32
    float* sum_re = abar + 2*P_DIM;
    float* sum_im = sum_re + NSCAN;
    float* car_re = sum_im + NSCAN;
    float* car_im = car_re + NSCAN;

    const int EW_U = (int)((BLD + 255)/256);
    const int CV   = (int)((NPKP + 255)/256);
    const int SC_G = (NSCAN + 255)/256;
    const size_t pd = (size_t)P_DIM*D_MODEL;
    dim3 gg(BL/TM, NP/TN);                 // (128, 9)

    encode_k<<<EW_U, 256, 0, stream>>>(x, enc_w, enc_b, h);

    for (int i = 0; i < NLAYER; ++i) {
        prep_k<<<CV, 256, 0, stream>>>(
            lam_re + i*P_DIM, lam_im + i*P_DIM, log_step + i*P_DIM,
            B_re + i*pd, B_im + i*pd, wbr, wbi, abar);
        const float* WencA = Wenc + (size_t)i*2*pd;
        const float* WencG = WencA + pd;
        convw5_k<<<dim3(CV,1,5), 256, 0, stream>>>(
            C_re + i*pd, C_im + i*pd, WencA, WencG, Wdec + i*pd, w5);

        // fx = LN(LN(h)) in one pass
        ln2x_k<<<BL, 256, 0, stream>>>(h, norm_w + i*D_MODEL, norm_b + i*D_MODEL,
                                       attn_w + i*D_MODEL, attn_b + i*D_MODEL, b2);

        // Bu_re, Bu_im in one dual-output GEMM
        gemm2o_k<0><<<gg, 256, 0, stream>>>(b2, wbr, wbi, b1, b3, P_DIM);

        // chunked parallel scan (in-place on b1/b3)
        scan_partial_k<<<SC_G, 256, 0, stream>>>(b1, b3, abar, sum_re, sum_im);
        scan_carry_k<<<(BSZ*P_DIM + 255)/256, 256, 0, stream>>>(sum_re, sum_im, abar, car_re, car_im);
        scan_apply_k<<<SC_G, 256, 0, stream>>>(b1, b3, abar, car_re, car_im);

        // z2 = gelu(xs_re@C_re^T + xs_im@(-C_im)^T + Dvec*fx) + fx
        gemmC_k<<<gg, 256, 0, stream>>>(b1, wcr, b3, wci, b2, Dvec + i*D_MODEL, b4, D_MODEL);

        // fy = LN(z2)
        ln_k<<<BL, 256, 0, stream>>>(b4, ff_w + i*D_MODEL, ff_b + i*D_MODEL, b1);

        // GEGLU MLP: b2 = (fy@WencA^T) * gelu(fy@WencG^T)
        gemm2o_k<1><<<gg, 256, 0, stream>>>(b1, wea, weg, b2, nullptr, D_MODEL);

        // h += b2@Wdec^T + fy
        gemmD_k<<<gg, 256, 0, stream>>>(b2, wd, b1, h, D_MODEL);
    }

    head_init_k<<<1, 64, 0, stream>>>(out, head_b);
    head_k<<<dim3(BSZ, 64), 256, 0, stream>>>(h, head_w, out);
}

// Round 6
// 2173.147 us; speedup vs baseline: 6.7438x; 1.0901x over previous
//
#include <hip/hip_runtime.h>
#include <hip/hip_bf16.h>
#include <cstddef>

typedef __hip_bfloat16 bf16;

// ---------------- problem constants ----------------
#define D_MODEL 1048
#define P_DIM   1048
#define NLAYER  3
#define BSZ     4
#define LSEQ    4096
#define BL      (BSZ*LSEQ)                 // 16384 rows
#define BLD     ((size_t)BL*D_MODEL)       // unpadded elements
#define KP      1056                       // padded K / row stride (mult of 32)
#define NP      1152                       // padded N for weights (mult of 128)
#define BLA     ((size_t)BL*KP)            // padded activation elements
#define NPKP    ((size_t)NP*KP)            // padded weight elements

// scan chunking
#define NC      64
#define CL      (LSEQ/NC)                  // 64
#define NSCAN   (BSZ*NC*P_DIM)

typedef __attribute__((ext_vector_type(8))) short short8;
typedef __attribute__((ext_vector_type(4))) float f32x4;

#define TM 128
#define TN 128
#define TK 32
#define TILE_SH (TM*TK)                    // 4096 shorts = 8 KB per sub-tile

__device__ __forceinline__ float gelu_f(float x) {
    return 0.5f * x * (1.f + erff(x * 0.70710678118654752f));
}

// ---------------- staging helper: one 128x32 bf16 tile via global_load_lds --
__device__ __forceinline__ void stage_tile(
    const bf16* __restrict__ src, int row0, int k0, short* lds, int tid)
{
#pragma unroll
    for (int c = 0; c < 2; ++c) {
        int chunk = tid + 256*c;          // 0..511
        int r = chunk >> 2;
        int col = (chunk & 3) * 8;
        __builtin_amdgcn_global_load_lds(
            (const __attribute__((address_space(1))) void*)(src + (size_t)(row0 + r)*KP + k0 + col),
            (__attribute__((address_space(3))) void*)(lds + chunk*8), 16, 0, 0);
    }
}

// ---------------- MFMA sub-steps (one TK=32 slice) ----------------
__device__ __forceinline__ void mfma_step1(
    const short* As, const short* Ws, f32x4 (&acc)[4][4],
    int wm, int wn, int row_in, int quad)
{
    short8 a[4], b[4];
#pragma unroll
    for (int i = 0; i < 4; ++i) {
        a[i] = *(const short8*)&As[(wm + i*16 + row_in)*TK + quad*8];
        b[i] = *(const short8*)&Ws[(wn + i*16 + row_in)*TK + quad*8];
    }
#pragma unroll
    for (int i = 0; i < 4; ++i)
#pragma unroll
        for (int j = 0; j < 4; ++j)
            acc[i][j] = __builtin_amdgcn_mfma_f32_16x16x32_bf16(a[i], b[j], acc[i][j], 0, 0, 0);
}

__device__ __forceinline__ void mfma_step2(
    const short* As, const short* W0s, const short* W1s,
    f32x4 (&acc0)[4][4], f32x4 (&acc1)[4][4],
    int wm, int wn, int row_in, int quad)
{
    short8 a[4], b0[4], b1[4];
#pragma unroll
    for (int i = 0; i < 4; ++i) {
        a[i]  = *(const short8*)&As [(wm + i*16 + row_in)*TK + quad*8];
        b0[i] = *(const short8*)&W0s[(wn + i*16 + row_in)*TK + quad*8];
        b1[i] = *(const short8*)&W1s[(wn + i*16 + row_in)*TK + quad*8];
    }
#pragma unroll
    for (int i = 0; i < 4; ++i)
#pragma unroll
        for (int j = 0; j < 4; ++j) {
            acc0[i][j] = __builtin_amdgcn_mfma_f32_16x16x32_bf16(a[i], b0[j], acc0[i][j], 0, 0, 0);
            acc1[i][j] = __builtin_amdgcn_mfma_f32_16x16x32_bf16(a[i], b1[j], acc1[i][j], 0, 0, 0);
        }
}

// ---------------- dual-output GEMM: acc0 = A@W0^T, acc1 = A@W1^T ------------
// MODE 0: store both (pads zeroed).  MODE 1: O0 = acc0 * gelu(acc1).
// BK=64: two TK=32 sub-tiles per barrier pair; tail iter covers k=1024..1055.
template <int MODE>
__global__ __launch_bounds__(256, 2) void gemm2o_k(
    const bf16* __restrict__ A, const bf16* __restrict__ W0,
    const bf16* __restrict__ W1,
    bf16* __restrict__ O0, bf16* __restrict__ O1, int N)
{
    __shared__ short As[2*TILE_SH];
    __shared__ short W0s[2*TILE_SH];
    __shared__ short W1s[2*TILE_SH];
    const int tid  = threadIdx.x;
    const int m0   = blockIdx.x * TM;
    const int n0   = blockIdx.y * TN;
    const int wave = tid >> 6, lane = tid & 63;
    const int wm = (wave >> 1) * 64, wn = (wave & 1) * 64;
    const int row_in = lane & 15, quad = lane >> 4;

    f32x4 acc0[4][4] = {};
    f32x4 acc1[4][4] = {};

    for (int kt = 0; kt < 16; ++kt) {
        const int k0 = kt*64;
        stage_tile(A,  m0, k0,      As,            tid);
        stage_tile(A,  m0, k0 + 32, As + TILE_SH,  tid);
        stage_tile(W0, n0, k0,      W0s,           tid);
        stage_tile(W0, n0, k0 + 32, W0s + TILE_SH, tid);
        stage_tile(W1, n0, k0,      W1s,           tid);
        stage_tile(W1, n0, k0 + 32, W1s + TILE_SH, tid);
        __syncthreads();
        mfma_step2(As,           W0s,           W1s,           acc0, acc1, wm, wn, row_in, quad);
        mfma_step2(As + TILE_SH, W0s + TILE_SH, W1s + TILE_SH, acc0, acc1, wm, wn, row_in, quad);
        __syncthreads();
    }
    // tail: k = 1024..1055
    stage_tile(A,  m0, 1024, As,  tid);
    stage_tile(W0, n0, 1024, W0s, tid);
    stage_tile(W1, n0, 1024, W1s, tid);
    __syncthreads();
    mfma_step2(As, W0s, W1s, acc0, acc1, wm, wn, row_in, quad);

#pragma unroll
    for (int i = 0; i < 4; ++i) {
#pragma unroll
        for (int j = 0; j < 4; ++j) {
            int n = n0 + wn + j*16 + row_in;
#pragma unroll
            for (int r = 0; r < 4; ++r) {
                int m = m0 + wm + i*16 + quad*4 + r;
                size_t o = (size_t)m*KP + n;
                if (MODE == 0) {
                    if (n < N)        { O0[o] = __float2bfloat16(acc0[i][j][r]);
                                        O1[o] = __float2bfloat16(acc1[i][j][r]); }
                    else if (n < KP)  { O0[o] = __float2bfloat16(0.f);
                                        O1[o] = __float2bfloat16(0.f); }
                } else {
                    if (n < N)        O0[o] = __float2bfloat16(acc0[i][j][r] * gelu_f(acc1[i][j][r]));
                    else if (n < KP)  O0[o] = __float2bfloat16(0.f);
                }
            }
        }
    }
}

// ---------------- dual-input GEMM + sepi epilogue ----------------
// acc = A0@W0^T + A1@W1^T;  O = gelu(acc + dv[n]*fx) + fx   (pads zeroed)
__global__ __launch_bounds__(256) void gemmC_k(
    const bf16* __restrict__ A0, const bf16* __restrict__ W0,
    const bf16* __restrict__ A1, const bf16* __restrict__ W1,
    const bf16* __restrict__ fx, const float* __restrict__ dv,
    bf16* __restrict__ O, int N)
{
    __shared__ short As[2*TILE_SH];
    __shared__ short Ws[2*TILE_SH];
    const int tid  = threadIdx.x;
    const int m0   = blockIdx.x * TM;
    const int n0   = blockIdx.y * TN;
    const int wave = tid >> 6, lane = tid & 63;
    const int wm = (wave >> 1) * 64, wn = (wave & 1) * 64;
    const int row_in = lane & 15, quad = lane >> 4;

    f32x4 acc[4][4] = {};

    for (int pair = 0; pair < 2; ++pair) {
        const bf16* A = pair ? A1 : A0;
        const bf16* W = pair ? W1 : W0;
        for (int kt = 0; kt < 16; ++kt) {
            const int k0 = kt*64;
            stage_tile(A, m0, k0,      As,           tid);
            stage_tile(A, m0, k0 + 32, As + TILE_SH, tid);
            stage_tile(W, n0, k0,      Ws,           tid);
            stage_tile(W, n0, k0 + 32, Ws + TILE_SH, tid);
            __syncthreads();
            mfma_step1(As,           Ws,           acc, wm, wn, row_in, quad);
            mfma_step1(As + TILE_SH, Ws + TILE_SH, acc, wm, wn, row_in, quad);
            __syncthreads();
        }
        stage_tile(A, m0, 1024, As, tid);
        stage_tile(W, n0, 1024, Ws, tid);
        __syncthreads();
        mfma_step1(As, Ws, acc, wm, wn, row_in, quad);
        __syncthreads();
    }

#pragma unroll
    for (int i = 0; i < 4; ++i) {
#pragma unroll
        for (int j = 0; j < 4; ++j) {
            int n = n0 + wn + j*16 + row_in;
#pragma unroll
            for (int r = 0; r < 4; ++r) {
                int m = m0 + wm + i*16 + quad*4 + r;
                size_t o = (size_t)m*KP + n;
                if (n < N) {
                    float f = __bfloat162float(fx[o]);
                    float t = acc[i][j][r] + dv[n]*f;
                    O[o] = __float2bfloat16(gelu_f(t) + f);
                } else if (n < KP) {
                    O[o] = __float2bfloat16(0.f);
                }
            }
        }
    }
}

// ---------------- single GEMM + residual epilogue: h += acc + fy -----------
__global__ __launch_bounds__(256) void gemmD_k(
    const bf16* __restrict__ A, const bf16* __restrict__ W,
    const bf16* __restrict__ fy, float* __restrict__ h, int N)
{
    __shared__ short As[2*TILE_SH];
    __shared__ short Ws[2*TILE_SH];
    const int tid  = threadIdx.x;
    const int m0   = blockIdx.x * TM;
    const int n0   = blockIdx.y * TN;
    const int wave = tid >> 6, lane = tid & 63;
    const int wm = (wave >> 1) * 64, wn = (wave & 1) * 64;
    const int row_in = lane & 15, quad = lane >> 4;

    f32x4 acc[4][4] = {};

    for (int kt = 0; kt < 16; ++kt) {
        const int k0 = kt*64;
        stage_tile(A, m0, k0,      As,           tid);
        stage_tile(A, m0, k0 + 32, As + TILE_SH, tid);
        stage_tile(W, n0, k0,      Ws,           tid);
        stage_tile(W, n0, k0 + 32, Ws + TILE_SH, tid);
        __syncthreads();
        mfma_step1(As,           Ws,           acc, wm, wn, row_in, quad);
        mfma_step1(As + TILE_SH, Ws + TILE_SH, acc, wm, wn, row_in, quad);
        __syncthreads();
    }
    stage_tile(A, m0, 1024, As, tid);
    stage_tile(W, n0, 1024, Ws, tid);
    __syncthreads();
    mfma_step1(As, Ws, acc, wm, wn, row_in, quad);

#pragma unroll
    for (int i = 0; i < 4; ++i) {
#pragma unroll
        for (int j = 0; j < 4; ++j) {
            int n = n0 + wn + j*16 + row_in;
            if (n >= N) continue;
#pragma unroll
            for (int r = 0; r < 4; ++r) {
                int m = m0 + wm + i*16 + quad*4 + r;
                float f = __bfloat162float(fy[(size_t)m*KP + n]);
                h[(size_t)m*D_MODEL + n] += acc[i][j][r] + f;
            }
        }
    }
}

// ---------------- batched weight conversion (5x 1048x1048 fp32 -> bf16) ----
__global__ __launch_bounds__(256) void convw5_k(
    const float* __restrict__ s0, const float* __restrict__ s1,
    const float* __restrict__ s2, const float* __restrict__ s3,
    const float* __restrict__ s4, bf16* __restrict__ dst)
{
    size_t i = (size_t)blockIdx.x*256 + threadIdx.x;
    if (i >= NPKP) return;
    int z = blockIdx.z;
    const float* src = (z == 0) ? s0 : (z == 1) ? s1 : (z == 2) ? s2 : (z == 3) ? s3 : s4;
    float scale = (z == 1) ? -1.f : 1.f;
    int n = (int)(i / KP), k = (int)(i - (size_t)n*KP);
    float v = (n < D_MODEL && k < D_MODEL) ? scale*src[(size_t)n*D_MODEL + k] : 0.f;
    dst[(size_t)z*NPKP + i] = __float2bfloat16(v);
}

// ---------------- reductions ----------------
__device__ __forceinline__ float2 block_reduce2(float a, float b) {
    __syncthreads();   // safe for repeated calls (shared reuse)
    for (int off = 32; off; off >>= 1) {
        a += __shfl_down(a, off, 64);
        b += __shfl_down(b, off, 64);
    }
    __shared__ float sa[4], sb[4];
    int lane = threadIdx.x & 63, wv = threadIdx.x >> 6;
    if (lane == 0) { sa[wv] = a; sb[wv] = b; }
    __syncthreads();
    if (threadIdx.x == 0) {
        sa[0] = sa[0]+sa[1]+sa[2]+sa[3];
        sb[0] = sb[0]+sb[1]+sb[2]+sb[3];
    }
    __syncthreads();
    return make_float2(sa[0], sb[0]);
}

// ---------------- encode ----------------
__global__ __launch_bounds__(256) void encode_k(
    const float* __restrict__ x, const float* __restrict__ ew,
    const float* __restrict__ eb, float* __restrict__ h)
{
    size_t i = (size_t)blockIdx.x*256 + threadIdx.x;
    if (i >= BLD) return;
    int d = (int)(i % D_MODEL);
    size_t bl = i / D_MODEL;
    h[i] = x[bl]*ew[d] + eb[d];
}

// ---------------- fused double layernorm: fx = LN(LN(h,w1,b1),w2,b2) -------
__global__ __launch_bounds__(256) void ln2x_k(
    const float* __restrict__ x,
    const float* __restrict__ w1, const float* __restrict__ bb1,
    const float* __restrict__ w2, const float* __restrict__ bb2,
    bf16* __restrict__ y)
{
    const size_t row = blockIdx.x;
    const float* xr = x + row * D_MODEL;
    float v[5];
    float s = 0.f, ss = 0.f;
    int i = 0;
    for (int d = threadIdx.x; d < KP; d += 256, ++i) {
        float t = (d < D_MODEL) ? xr[d] : 0.f;
        v[i] = t; s += t; ss += t*t;
    }
    float2 r = block_reduce2(s, ss);
    float mu  = r.x * (1.f/D_MODEL);
    float var = r.y * (1.f/D_MODEL) - mu*mu;
    float inv = rsqrtf(var + 1e-5f);
    s = 0.f; ss = 0.f; i = 0;
    for (int d = threadIdx.x; d < KP; d += 256, ++i) {
        float z = (d < D_MODEL) ? (v[i]-mu)*inv*w1[d] + bb1[d] : 0.f;
        v[i] = z; s += z; ss += z*z;
    }
    r = block_reduce2(s, ss);
    mu  = r.x * (1.f/D_MODEL);
    var = r.y * (1.f/D_MODEL) - mu*mu;
    inv = rsqrtf(var + 1e-5f);
    bf16* yr = y + row * KP;
    i = 0;
    for (int d = threadIdx.x; d < KP; d += 256, ++i) {
        float o = (d < D_MODEL) ? (v[i]-mu)*inv*w2[d] + bb2[d] : 0.f;
        yr[d] = __float2bfloat16(o);
    }
}

// ---------------- single layernorm (bf16 in stride KP) ----------------
__global__ __launch_bounds__(256) void ln_k(
    const bf16* __restrict__ x, const float* __restrict__ w,
    const float* __restrict__ b, bf16* __restrict__ y)
{
    const size_t row = blockIdx.x;
    const bf16* xr = x + row * KP;
    float v[5];
    float s = 0.f, ss = 0.f;
    int i = 0;
    for (int d = threadIdx.x; d < KP; d += 256, ++i) {
        float t = (d < D_MODEL) ? __bfloat162float(xr[d]) : 0.f;
        v[i] = t; s += t; ss += t*t;
    }
    float2 r = block_reduce2(s, ss);
    float mu  = r.x * (1.f/D_MODEL);
    float var = r.y * (1.f/D_MODEL) - mu*mu;
    float inv = rsqrtf(var + 1e-5f);
    bf16* yr = y + row * KP;
    i = 0;
    for (int d = threadIdx.x; d < KP; d += 256, ++i) {
        float o = (d < D_MODEL) ? (v[i]-mu)*inv*w[d] + b[d] : 0.f;
        yr[d] = __float2bfloat16(o);
    }
}

// ---------------- per-layer SSM precompute (padded Bbar) ----------------
__global__ __launch_bounds__(256) void prep_k(
    const float* __restrict__ lam_re, const float* __restrict__ lam_im,
    const float* __restrict__ log_step,
    const float* __restrict__ B_re, const float* __restrict__ B_im,
    bf16* __restrict__ bbar_re, bf16* __restrict__ bbar_im,
    float* __restrict__ abar)
{
    size_t idx = (size_t)blockIdx.x*256 + threadIdx.x;
    if (idx >= NPKP) return;
    int p = (int)(idx / KP);
    int d = (int)(idx - (size_t)p*KP);
    if (p >= P_DIM || d >= D_MODEL) {
        bbar_re[idx] = __float2bfloat16(0.f);
        bbar_im[idx] = __float2bfloat16(0.f);
        return;
    }
    float lr = lam_re[p], li = lam_im[p];
    float st = expf(log_step[p]);
    float er = expf(lr*st);
    float ar = er * cosf(li*st);
    float ai = er * sinf(li*st);
    if (d == 0) { abar[p] = ar; abar[P_DIM + p] = ai; }
    float den = lr*lr + li*li;
    float xr = ar - 1.f, xi = ai;
    float cr = (xr*lr + xi*li) / den;
    float ci = (xi*lr - xr*li) / den;
    float br = B_re[(size_t)p*D_MODEL + d], bi = B_im[(size_t)p*D_MODEL + d];
    bbar_re[idx] = __float2bfloat16(cr*br - ci*bi);
    bbar_im[idx] = __float2bfloat16(cr*bi + ci*br);
}

// ---------------- chunked parallel scan ----------------
__global__ __launch_bounds__(256) void scan_partial_k(
    const bf16* __restrict__ ur, const bf16* __restrict__ ui,
    const float* __restrict__ abar,
    float* __restrict__ sum_re, float* __restrict__ sum_im)
{
    int idx = blockIdx.x*256 + threadIdx.x;
    if (idx >= NSCAN) return;
    int p = idx % P_DIM;
    int rest = idx / P_DIM;
    int c = rest % NC, b = rest / NC;
    float ar = abar[p], ai = abar[P_DIM + p];
    size_t base = ((size_t)b*LSEQ + (size_t)c*CL)*KP + p;
    float sre = 0.f, sim = 0.f;
    for (int i = 0; i < CL; ++i) {
        size_t o = base + (size_t)i*KP;
        float br = __bfloat162float(ur[o]);
        float bi = __bfloat162float(ui[o]);
        float nr = fmaf(ar, sre, fmaf(-ai, sim, br));
        float ni = fmaf(ar, sim, fmaf( ai, sre, bi));
        sre = nr; sim = ni;
    }
    sum_re[idx] = sre; sum_im[idx] = sim;
}

__global__ __launch_bounds__(256) void scan_carry_k(
    const float* __restrict__ sum_re, const float* __restrict__ sum_im,
    const float* __restrict__ abar,
    float* __restrict__ car_re, float* __restrict__ car_im)
{
    int idx = blockIdx.x*256 + threadIdx.x;
    if (idx >= BSZ*P_DIM) return;
    int p = idx % P_DIM, b = idx / P_DIM;
    float cr = abar[p], ci = abar[P_DIM + p];
#pragma unroll
    for (int s = 0; s < 6; ++s) {
        float nr = cr*cr - ci*ci;
        float ni = 2.f*cr*ci;
        cr = nr; ci = ni;
    }
    float xre = 0.f, xim = 0.f;
    size_t base = (size_t)b*NC*P_DIM + p;
    for (int c = 0; c < NC; ++c) {
        size_t o = base + (size_t)c*P_DIM;
        car_re[o] = xre; car_im[o] = xim;
        float sre = sum_re[o], sim = sum_im[o];
        float nr = fmaf(cr, xre, fmaf(-ci, xim, sre));
        float ni = fmaf(cr, xim, fmaf( ci, xre, sim));
        xre = nr; xim = ni;
    }
}

__global__ __launch_bounds__(256) void scan_apply_k(
    bf16* __restrict__ ur, bf16* __restrict__ ui,
    const float* __restrict__ abar,
    const float* __restrict__ car_re, const float* __restrict__ car_im)
{
    int idx = blockIdx.x*256 + threadIdx.x;
    if (idx >= NSCAN) return;
    int p = idx % P_DIM;
    int rest = idx / P_DIM;
    int c = rest % NC, b = rest / NC;
    float ar = abar[p], ai = abar[P_DIM + p];
    size_t co = (size_t)b*NC*P_DIM + (size_t)c*P_DIM + p;
    float xre = car_re[co], xim = car_im[co];
    size_t base = ((size_t)b*LSEQ + (size_t)c*CL)*KP + p;
    for (int i = 0; i < CL; ++i) {
        size_t o = base + (size_t)i*KP;
        float br = __bfloat162float(ur[o]);
        float bi = __bfloat162float(ui[o]);
        float nr = fmaf(ar, xre, fmaf(-ai, xim, br));
        float ni = fmaf(ar, xim, fmaf( ai, xre, bi));
        xre = nr; xim = ni;
        ur[o] = __float2bfloat16(xre);
        ui[o] = __float2bfloat16(xim);
    }
}

// ---------------- head ----------------
__global__ void head_init_k(float* out, const float* hb)
{
    if (threadIdx.x < BSZ) out[threadIdx.x] = hb[0];
}

__global__ __launch_bounds__(256) void head_k(
    const float* __restrict__ h, const float* __restrict__ hw,
    float* __restrict__ out)
{
    int b = blockIdx.x;
    int chunk = blockIdx.y;
    const float* hb = h + ((size_t)b*LSEQ + (size_t)chunk*64)*D_MODEL;
    float s = 0.f;
    for (int l = 0; l < 64; ++l) {
        const float* hr = hb + (size_t)l*D_MODEL;
        for (int d = threadIdx.x; d < D_MODEL; d += 256)
            s += hr[d]*hw[d];
    }
    for (int off = 32; off; off >>= 1) s += __shfl_down(s, off, 64);
    __shared__ float sm[4];
    int lane = threadIdx.x & 63, wv = threadIdx.x >> 6;
    if (lane == 0) sm[wv] = s;
    __syncthreads();
    if (threadIdx.x == 0)
        atomicAdd(out + b, (sm[0]+sm[1]+sm[2]+sm[3]) * (1.f/LSEQ));
}

// ---------------- launch ----------------
extern "C" void kernel_launch(void* const* d_in, const int* in_sizes, int n_in,
                              void* d_out, int out_size, void* d_ws, size_t ws_size,
                              hipStream_t stream)
{
    const float* x          = (const float*)d_in[0];
    const float* enc_w      = (const float*)d_in[1];
    const float* enc_b      = (const float*)d_in[2];
    const float* norm_w     = (const float*)d_in[3];
    const float* norm_b     = (const float*)d_in[4];
    const float* attn_w     = (const float*)d_in[5];
    const float* attn_b     = (const float*)d_in[6];
    const float* ff_w       = (const float*)d_in[7];
    const float* ff_b       = (const float*)d_in[8];
    const float* lam_re     = (const float*)d_in[9];
    const float* lam_im     = (const float*)d_in[10];
    const float* log_step   = (const float*)d_in[11];
    const float* B_re       = (const float*)d_in[12];
    const float* B_im       = (const float*)d_in[13];
    const float* C_re       = (const float*)d_in[14];
    const float* C_im       = (const float*)d_in[15];
    const float* Dvec       = (const float*)d_in[16];
    const float* Wenc       = (const float*)d_in[17];
    const float* Wdec       = (const float*)d_in[18];
    const float* head_w     = (const float*)d_in[19];
    const float* head_b     = (const float*)d_in[20];
    float* out = (float*)d_out;

    // ---- workspace (~233 MB) ----
    float* h    = (float*)d_ws;            // BLD fp32
    bf16*  b1   = (bf16*)(h + BLD);        // BLA bf16 each
    bf16*  b2   = b1 + BLA;
    bf16*  b3   = b2 + BLA;
    bf16*  b4   = b3 + BLA;
    bf16*  wbr  = b4 + BLA;                // Bbar re/im
    bf16*  wbi  = wbr + NPKP;
    bf16*  w5   = wbi + NPKP;              // wcr,wci(-),wea,weg,wd contiguous
    bf16*  wcr  = w5;
    bf16*  wci  = w5 + NPKP;
    bf16*  wea  = w5 + 2*NPKP;
    bf16*  weg  = w5 + 3*NPKP;
    bf16*  wd   = w5 + 4*NPKP;
    float* abar = (float*)(w5 + 5*NPKP);   // 2*P fp32
    float* sum_re = abar + 2*P_DIM;
    float* sum_im = sum_re + NSCAN;
    float* car_re = sum_im + NSCAN;
    float* car_im = car_re + NSCAN;

    const int EW_U = (int)((BLD + 255)/256);
    const int CV   = (int)((NPKP + 255)/256);
    const int SC_G = (NSCAN + 255)/256;
    const size_t pd = (size_t)P_DIM*D_MODEL;
    dim3 gg(BL/TM, NP/TN);                 // (128, 9)

    encode_k<<<EW_U, 256, 0, stream>>>(x, enc_w, enc_b, h);

    for (int i = 0; i < NLAYER; ++i) {
        prep_k<<<CV, 256, 0, stream>>>(
            lam_re + i*P_DIM, lam_im + i*P_DIM, log_step + i*P_DIM,
            B_re + i*pd, B_im + i*pd, wbr, wbi, abar);
        const float* WencA = Wenc + (size_t)i*2*pd;
        const float* WencG = WencA + pd;
        convw5_k<<<dim3(CV,1,5), 256, 0, stream>>>(
            C_re + i*pd, C_im + i*pd, WencA, WencG, Wdec + i*pd, w5);

        // fx = LN(LN(h)) in one pass
        ln2x_k<<<BL, 256, 0, stream>>>(h, norm_w + i*D_MODEL, norm_b + i*D_MODEL,
                                       attn_w + i*D_MODEL, attn_b + i*D_MODEL, b2);

        // Bu_re, Bu_im in one dual-output GEMM
        gemm2o_k<0><<<gg, 256, 0, stream>>>(b2, wbr, wbi, b1, b3, P_DIM);

        // chunked parallel scan (in-place on b1/b3)
        scan_partial_k<<<SC_G, 256, 0, stream>>>(b1, b3, abar, sum_re, sum_im);
        scan_carry_k<<<(BSZ*P_DIM + 255)/256, 256, 0, stream>>>(sum_re, sum_im, abar, car_re, car_im);
        scan_apply_k<<<SC_G, 256, 0, stream>>>(b1, b3, abar, car_re, car_im);

        // z2 = gelu(xs_re@C_re^T + xs_im@(-C_im)^T + Dvec*fx) + fx
        gemmC_k<<<gg, 256, 0, stream>>>(b1, wcr, b3, wci, b2, Dvec + i*D_MODEL, b4, D_MODEL);

        // fy = LN(z2)
        ln_k<<<BL, 256, 0, stream>>>(b4, ff_w + i*D_MODEL, ff_b + i*D_MODEL, b1);

        // GEGLU MLP: b2 = (fy@WencA^T) * gelu(fy@WencG^T)
        gemm2o_k<1><<<gg, 256, 0, stream>>>(b1, wea, weg, b2, nullptr, D_MODEL);

        // h += b2@Wdec^T + fy
        gemmD_k<<<gg, 256, 0, stream>>>(b2, wd, b1, h, D_MODEL);
    }

    head_init_k<<<1, 64, 0, stream>>>(out, head_b);
    head_k<<<dim3(BSZ, 64), 256, 0, stream>>>(h, head_w, out);
}

// Round 7
// 2158.487 us; speedup vs baseline: 6.7896x; 1.0068x over previous
//
#include <hip/hip_runtime.h>
#include <hip/hip_bf16.h>
#include <cstddef>

typedef __hip_bfloat16 bf16;

// ---------------- problem constants ----------------
#define D_MODEL 1048
#define P_DIM   1048
#define NLAYER  3
#define BSZ     4
#define LSEQ    4096
#define BL      (BSZ*LSEQ)                 // 16384 rows
#define BLD     ((size_t)BL*D_MODEL)       // unpadded elements
#define KP      1056                       // padded K / row stride (mult of 32)
#define NP      1152                       // padded N for weights (mult of 128)
#define BLA     ((size_t)BL*KP)            // padded activation elements
#define NPKP    ((size_t)NP*KP)            // padded weight elements

// scan chunking
#define NC      64
#define CL      (LSEQ/NC)                  // 64
#define NSCAN   (BSZ*NC*P_DIM)

typedef __attribute__((ext_vector_type(8))) short short8;
typedef __attribute__((ext_vector_type(4))) float f32x4;

#define TM 128
#define TN 128
#define TK 32
#define TILE_SH (TM*TK)                    // 4096 shorts = 8 KB per sub-tile
#define NGEMM   ((BL/TM)*(NP/TN))          // 1152 blocks

__device__ __forceinline__ float gelu_f(float x) {
    return 0.5f * x * (1.f + erff(x * 0.70710678118654752f));
}

// XCD-aware tile mapping: 9 blocks sharing one A m-tile are consecutive on
// one XCD (assumes round-robin xcd = blockId % 8).  A-tile -> 1 L3 read + 8
// L2 hits; W stays L2-resident across the XCD's 16 m-groups.
__device__ __forceinline__ void tile_coords(int id, int& m0, int& n0) {
    int xcd  = id & 7;
    int slot = id >> 3;          // 0..143
    int xg   = slot / 9;         // 0..15
    int j    = slot - xg*9;      // 0..8
    m0 = (xg*8 + xcd) * TM;
    n0 = j * TN;
}

// ---------------- staging helper: one 128x32 bf16 tile via global_load_lds --
__device__ __forceinline__ void stage_tile(
    const bf16* __restrict__ src, int row0, int k0, short* lds, int tid)
{
#pragma unroll
    for (int c = 0; c < 2; ++c) {
        int chunk = tid + 256*c;          // 0..511
        int r = chunk >> 2;
        int col = (chunk & 3) * 8;
        __builtin_amdgcn_global_load_lds(
            (const __attribute__((address_space(1))) void*)(src + (size_t)(row0 + r)*KP + k0 + col),
            (__attribute__((address_space(3))) void*)(lds + chunk*8), 16, 0, 0);
    }
}

// ---------------- MFMA sub-steps (one TK=32 slice) ----------------
__device__ __forceinline__ void mfma_step1(
    const short* As, const short* Ws, f32x4 (&acc)[4][4],
    int wm, int wn, int row_in, int quad)
{
    short8 a[4], b[4];
#pragma unroll
    for (int i = 0; i < 4; ++i) {
        a[i] = *(const short8*)&As[(wm + i*16 + row_in)*TK + quad*8];
        b[i] = *(const short8*)&Ws[(wn + i*16 + row_in)*TK + quad*8];
    }
#pragma unroll
    for (int i = 0; i < 4; ++i)
#pragma unroll
        for (int j = 0; j < 4; ++j)
            acc[i][j] = __builtin_amdgcn_mfma_f32_16x16x32_bf16(a[i], b[j], acc[i][j], 0, 0, 0);
}

__device__ __forceinline__ void mfma_step2(
    const short* As, const short* W0s, const short* W1s,
    f32x4 (&acc0)[4][4], f32x4 (&acc1)[4][4],
    int wm, int wn, int row_in, int quad)
{
    short8 a[4], b0[4], b1[4];
#pragma unroll
    for (int i = 0; i < 4; ++i) {
        a[i]  = *(const short8*)&As [(wm + i*16 + row_in)*TK + quad*8];
        b0[i] = *(const short8*)&W0s[(wn + i*16 + row_in)*TK + quad*8];
        b1[i] = *(const short8*)&W1s[(wn + i*16 + row_in)*TK + quad*8];
    }
#pragma unroll
    for (int i = 0; i < 4; ++i)
#pragma unroll
        for (int j = 0; j < 4; ++j) {
            acc0[i][j] = __builtin_amdgcn_mfma_f32_16x16x32_bf16(a[i], b0[j], acc0[i][j], 0, 0, 0);
            acc1[i][j] = __builtin_amdgcn_mfma_f32_16x16x32_bf16(a[i], b1[j], acc1[i][j], 0, 0, 0);
        }
}

// ---------------- dual-output GEMM: acc0 = A@W0^T, acc1 = A@W1^T ------------
// MODE 0: store both (pads zeroed).  MODE 1: O0 = acc0 * gelu(acc1).
template <int MODE>
__global__ __launch_bounds__(256, 2) void gemm2o_k(
    const bf16* __restrict__ A, const bf16* __restrict__ W0,
    const bf16* __restrict__ W1,
    bf16* __restrict__ O0, bf16* __restrict__ O1, int N)
{
    __shared__ short As[2*TILE_SH];
    __shared__ short W0s[2*TILE_SH];
    __shared__ short W1s[2*TILE_SH];
    const int tid  = threadIdx.x;
    int m0, n0;
    tile_coords(blockIdx.x, m0, n0);
    const int wave = tid >> 6, lane = tid & 63;
    const int wm = (wave >> 1) * 64, wn = (wave & 1) * 64;
    const int row_in = lane & 15, quad = lane >> 4;

    f32x4 acc0[4][4] = {};
    f32x4 acc1[4][4] = {};

    for (int kt = 0; kt < 16; ++kt) {
        const int k0 = kt*64;
        stage_tile(A,  m0, k0,      As,            tid);
        stage_tile(A,  m0, k0 + 32, As + TILE_SH,  tid);
        stage_tile(W0, n0, k0,      W0s,           tid);
        stage_tile(W0, n0, k0 + 32, W0s + TILE_SH, tid);
        stage_tile(W1, n0, k0,      W1s,           tid);
        stage_tile(W1, n0, k0 + 32, W1s + TILE_SH, tid);
        __syncthreads();
        mfma_step2(As,           W0s,           W1s,           acc0, acc1, wm, wn, row_in, quad);
        mfma_step2(As + TILE_SH, W0s + TILE_SH, W1s + TILE_SH, acc0, acc1, wm, wn, row_in, quad);
        __syncthreads();
    }
    // tail: k = 1024..1055
    stage_tile(A,  m0, 1024, As,  tid);
    stage_tile(W0, n0, 1024, W0s, tid);
    stage_tile(W1, n0, 1024, W1s, tid);
    __syncthreads();
    mfma_step2(As, W0s, W1s, acc0, acc1, wm, wn, row_in, quad);

#pragma unroll
    for (int i = 0; i < 4; ++i) {
#pragma unroll
        for (int j = 0; j < 4; ++j) {
            int n = n0 + wn + j*16 + row_in;
#pragma unroll
            for (int r = 0; r < 4; ++r) {
                int m = m0 + wm + i*16 + quad*4 + r;
                size_t o = (size_t)m*KP + n;
                if (MODE == 0) {
                    if (n < N)        { O0[o] = __float2bfloat16(acc0[i][j][r]);
                                        O1[o] = __float2bfloat16(acc1[i][j][r]); }
                    else if (n < KP)  { O0[o] = __float2bfloat16(0.f);
                                        O1[o] = __float2bfloat16(0.f); }
                } else {
                    if (n < N)        O0[o] = __float2bfloat16(acc0[i][j][r] * gelu_f(acc1[i][j][r]));
                    else if (n < KP)  O0[o] = __float2bfloat16(0.f);
                }
            }
        }
    }
}

// ---------------- dual-input GEMM + sepi epilogue ----------------
// acc = A0@W0^T + A1@W1^T;  O = gelu(acc + dv[n]*fx) + fx   (pads zeroed)
__global__ __launch_bounds__(256) void gemmC_k(
    const bf16* __restrict__ A0, const bf16* __restrict__ W0,
    const bf16* __restrict__ A1, const bf16* __restrict__ W1,
    const bf16* __restrict__ fx, const float* __restrict__ dv,
    bf16* __restrict__ O, int N)
{
    __shared__ short As[2*TILE_SH];
    __shared__ short Ws[2*TILE_SH];
    const int tid  = threadIdx.x;
    int m0, n0;
    tile_coords(blockIdx.x, m0, n0);
    const int wave = tid >> 6, lane = tid & 63;
    const int wm = (wave >> 1) * 64, wn = (wave & 1) * 64;
    const int row_in = lane & 15, quad = lane >> 4;

    f32x4 acc[4][4] = {};

    for (int pair = 0; pair < 2; ++pair) {
        const bf16* A = pair ? A1 : A0;
        const bf16* W = pair ? W1 : W0;
        for (int kt = 0; kt < 16; ++kt) {
            const int k0 = kt*64;
            stage_tile(A, m0, k0,      As,           tid);
            stage_tile(A, m0, k0 + 32, As + TILE_SH, tid);
            stage_tile(W, n0, k0,      Ws,           tid);
            stage_tile(W, n0, k0 + 32, Ws + TILE_SH, tid);
            __syncthreads();
            mfma_step1(As,           Ws,           acc, wm, wn, row_in, quad);
            mfma_step1(As + TILE_SH, Ws + TILE_SH, acc, wm, wn, row_in, quad);
            __syncthreads();
        }
        stage_tile(A, m0, 1024, As, tid);
        stage_tile(W, n0, 1024, Ws, tid);
        __syncthreads();
        mfma_step1(As, Ws, acc, wm, wn, row_in, quad);
        __syncthreads();
    }

#pragma unroll
    for (int i = 0; i < 4; ++i) {
#pragma unroll
        for (int j = 0; j < 4; ++j) {
            int n = n0 + wn + j*16 + row_in;
#pragma unroll
            for (int r = 0; r < 4; ++r) {
                int m = m0 + wm + i*16 + quad*4 + r;
                size_t o = (size_t)m*KP + n;
                if (n < N) {
                    float f = __bfloat162float(fx[o]);
                    float t = acc[i][j][r] + dv[n]*f;
                    O[o] = __float2bfloat16(gelu_f(t) + f);
                } else if (n < KP) {
                    O[o] = __float2bfloat16(0.f);
                }
            }
        }
    }
}

// ---------------- single GEMM + residual epilogue: h += acc + fy -----------
__global__ __launch_bounds__(256) void gemmD_k(
    const bf16* __restrict__ A, const bf16* __restrict__ W,
    const bf16* __restrict__ fy, float* __restrict__ h, int N)
{
    __shared__ short As[2*TILE_SH];
    __shared__ short Ws[2*TILE_SH];
    const int tid  = threadIdx.x;
    int m0, n0;
    tile_coords(blockIdx.x, m0, n0);
    const int wave = tid >> 6, lane = tid & 63;
    const int wm = (wave >> 1) * 64, wn = (wave & 1) * 64;
    const int row_in = lane & 15, quad = lane >> 4;

    f32x4 acc[4][4] = {};

    for (int kt = 0; kt < 16; ++kt) {
        const int k0 = kt*64;
        stage_tile(A, m0, k0,      As,           tid);
        stage_tile(A, m0, k0 + 32, As + TILE_SH, tid);
        stage_tile(W, n0, k0,      Ws,           tid);
        stage_tile(W, n0, k0 + 32, Ws + TILE_SH, tid);
        __syncthreads();
        mfma_step1(As,           Ws,           acc, wm, wn, row_in, quad);
        mfma_step1(As + TILE_SH, Ws + TILE_SH, acc, wm, wn, row_in, quad);
        __syncthreads();
    }
    stage_tile(A, m0, 1024, As, tid);
    stage_tile(W, n0, 1024, Ws, tid);
    __syncthreads();
    mfma_step1(As, Ws, acc, wm, wn, row_in, quad);

#pragma unroll
    for (int i = 0; i < 4; ++i) {
#pragma unroll
        for (int j = 0; j < 4; ++j) {
            int n = n0 + wn + j*16 + row_in;
            if (n >= N) continue;
#pragma unroll
            for (int r = 0; r < 4; ++r) {
                int m = m0 + wm + i*16 + quad*4 + r;
                float f = __bfloat162float(fy[(size_t)m*KP + n]);
                h[(size_t)m*D_MODEL + n] += acc[i][j][r] + f;
            }
        }
    }
}

// ---------------- batched weight conversion (5x 1048x1048 fp32 -> bf16) ----
__global__ __launch_bounds__(256) void convw5_k(
    const float* __restrict__ s0, const float* __restrict__ s1,
    const float* __restrict__ s2, const float* __restrict__ s3,
    const float* __restrict__ s4, bf16* __restrict__ dst)
{
    size_t i = (size_t)blockIdx.x*256 + threadIdx.x;
    if (i >= NPKP) return;
    int z = blockIdx.z;
    const float* src = (z == 0) ? s0 : (z == 1) ? s1 : (z == 2) ? s2 : (z == 3) ? s3 : s4;
    float scale = (z == 1) ? -1.f : 1.f;
    int n = (int)(i / KP), k = (int)(i - (size_t)n*KP);
    float v = (n < D_MODEL && k < D_MODEL) ? scale*src[(size_t)n*D_MODEL + k] : 0.f;
    dst[(size_t)z*NPKP + i] = __float2bfloat16(v);
}

// ---------------- reductions ----------------
__device__ __forceinline__ float2 block_reduce2(float a, float b) {
    __syncthreads();   // safe for repeated calls (shared reuse)
    for (int off = 32; off; off >>= 1) {
        a += __shfl_down(a, off, 64);
        b += __shfl_down(b, off, 64);
    }
    __shared__ float sa[4], sb[4];
    int lane = threadIdx.x & 63, wv = threadIdx.x >> 6;
    if (lane == 0) { sa[wv] = a; sb[wv] = b; }
    __syncthreads();
    if (threadIdx.x == 0) {
        sa[0] = sa[0]+sa[1]+sa[2]+sa[3];
        sb[0] = sb[0]+sb[1]+sb[2]+sb[3];
    }
    __syncthreads();
    return make_float2(sa[0], sb[0]);
}

// ---------------- encode ----------------
__global__ __launch_bounds__(256) void encode_k(
    const float* __restrict__ x, const float* __restrict__ ew,
    const float* __restrict__ eb, float* __restrict__ h)
{
    size_t i = (size_t)blockIdx.x*256 + threadIdx.x;
    if (i >= BLD) return;
    int d = (int)(i % D_MODEL);
    size_t bl = i / D_MODEL;
    h[i] = x[bl]*ew[d] + eb[d];
}

// ---------------- fused double layernorm: fx = LN(LN(h,w1,b1),w2,b2) -------
__global__ __launch_bounds__(256) void ln2x_k(
    const float* __restrict__ x,
    const float* __restrict__ w1, const float* __restrict__ bb1,
    const float* __restrict__ w2, const float* __restrict__ bb2,
    bf16* __restrict__ y)
{
    const size_t row = blockIdx.x;
    const float* xr = x + row * D_MODEL;
    float v[5];
    float s = 0.f, ss = 0.f;
    int i = 0;
    for (int d = threadIdx.x; d < KP; d += 256, ++i) {
        float t = (d < D_MODEL) ? xr[d] : 0.f;
        v[i] = t; s += t; ss += t*t;
    }
    float2 r = block_reduce2(s, ss);
    float mu  = r.x * (1.f/D_MODEL);
    float var = r.y * (1.f/D_MODEL) - mu*mu;
    float inv = rsqrtf(var + 1e-5f);
    s = 0.f; ss = 0.f; i = 0;
    for (int d = threadIdx.x; d < KP; d += 256, ++i) {
        float z = (d < D_MODEL) ? (v[i]-mu)*inv*w1[d] + bb1[d] : 0.f;
        v[i] = z; s += z; ss += z*z;
    }
    r = block_reduce2(s, ss);
    mu  = r.x * (1.f/D_MODEL);
    var = r.y * (1.f/D_MODEL) - mu*mu;
    inv = rsqrtf(var + 1e-5f);
    bf16* yr = y + row * KP;
    i = 0;
    for (int d = threadIdx.x; d < KP; d += 256, ++i) {
        float o = (d < D_MODEL) ? (v[i]-mu)*inv*w2[d] + bb2[d] : 0.f;
        yr[d] = __float2bfloat16(o);
    }
}

// ---------------- single layernorm (bf16 in stride KP) ----------------
__global__ __launch_bounds__(256) void ln_k(
    const bf16* __restrict__ x, const float* __restrict__ w,
    const float* __restrict__ b, bf16* __restrict__ y)
{
    const size_t row = blockIdx.x;
    const bf16* xr = x + row * KP;
    float v[5];
    float s = 0.f, ss = 0.f;
    int i = 0;
    for (int d = threadIdx.x; d < KP; d += 256, ++i) {
        float t = (d < D_MODEL) ? __bfloat162float(xr[d]) : 0.f;
        v[i] = t; s += t; ss += t*t;
    }
    float2 r = block_reduce2(s, ss);
    float mu  = r.x * (1.f/D_MODEL);
    float var = r.y * (1.f/D_MODEL) - mu*mu;
    float inv = rsqrtf(var + 1e-5f);
    bf16* yr = y + row * KP;
    i = 0;
    for (int d = threadIdx.x; d < KP; d += 256, ++i) {
        float o = (d < D_MODEL) ? (v[i]-mu)*inv*w[d] + b[d] : 0.f;
        yr[d] = __float2bfloat16(o);
    }
}

// ---------------- per-layer SSM precompute (padded Bbar) ----------------
__global__ __launch_bounds__(256) void prep_k(
    const float* __restrict__ lam_re, const float* __restrict__ lam_im,
    const float* __restrict__ log_step,
    const float* __restrict__ B_re, const float* __restrict__ B_im,
    bf16* __restrict__ bbar_re, bf16* __restrict__ bbar_im,
    float* __restrict__ abar)
{
    size_t idx = (size_t)blockIdx.x*256 + threadIdx.x;
    if (idx >= NPKP) return;
    int p = (int)(idx / KP);
    int d = (int)(idx - (size_t)p*KP);
    if (p >= P_DIM || d >= D_MODEL) {
        bbar_re[idx] = __float2bfloat16(0.f);
        bbar_im[idx] = __float2bfloat16(0.f);
        return;
    }
    float lr = lam_re[p], li = lam_im[p];
    float st = expf(log_step[p]);
    float er = expf(lr*st);
    float ar = er * cosf(li*st);
    float ai = er * sinf(li*st);
    if (d == 0) { abar[p] = ar; abar[P_DIM + p] = ai; }
    float den = lr*lr + li*li;
    float xr = ar - 1.f, xi = ai;
    float cr = (xr*lr + xi*li) / den;
    float ci = (xi*lr - xr*li) / den;
    float br = B_re[(size_t)p*D_MODEL + d], bi = B_im[(size_t)p*D_MODEL + d];
    bbar_re[idx] = __float2bfloat16(cr*br - ci*bi);
    bbar_im[idx] = __float2bfloat16(cr*bi + ci*br);
}

// ---------------- chunked parallel scan ----------------
__global__ __launch_bounds__(256) void scan_partial_k(
    const bf16* __restrict__ ur, const bf16* __restrict__ ui,
    const float* __restrict__ abar,
    float* __restrict__ sum_re, float* __restrict__ sum_im)
{
    int idx = blockIdx.x*256 + threadIdx.x;
    if (idx >= NSCAN) return;
    int p = idx % P_DIM;
    int rest = idx / P_DIM;
    int c = rest % NC, b = rest / NC;
    float ar = abar[p], ai = abar[P_DIM + p];
    size_t base = ((size_t)b*LSEQ + (size_t)c*CL)*KP + p;
    float sre = 0.f, sim = 0.f;
    for (int i = 0; i < CL; ++i) {
        size_t o = base + (size_t)i*KP;
        float br = __bfloat162float(ur[o]);
        float bi = __bfloat162float(ui[o]);
        float nr = fmaf(ar, sre, fmaf(-ai, sim, br));
        float ni = fmaf(ar, sim, fmaf( ai, sre, bi));
        sre = nr; sim = ni;
    }
    sum_re[idx] = sre; sum_im[idx] = sim;
}

__global__ __launch_bounds__(256) void scan_carry_k(
    const float* __restrict__ sum_re, const float* __restrict__ sum_im,
    const float* __restrict__ abar,
    float* __restrict__ car_re, float* __restrict__ car_im)
{
    int idx = blockIdx.x*256 + threadIdx.x;
    if (idx >= BSZ*P_DIM) return;
    int p = idx % P_DIM, b = idx / P_DIM;
    float cr = abar[p], ci = abar[P_DIM + p];
#pragma unroll
    for (int s = 0; s < 6; ++s) {
        float nr = cr*cr - ci*ci;
        float ni = 2.f*cr*ci;
        cr = nr; ci = ni;
    }
    float xre = 0.f, xim = 0.f;
    size_t base = (size_t)b*NC*P_DIM + p;
    for (int c = 0; c < NC; ++c) {
        size_t o = base + (size_t)c*P_DIM;
        car_re[o] = xre; car_im[o] = xim;
        float sre = sum_re[o], sim = sum_im[o];
        float nr = fmaf(cr, xre, fmaf(-ci, xim, sre));
        float ni = fmaf(cr, xim, fmaf( ci, xre, sim));
        xre = nr; xim = ni;
    }
}

__global__ __launch_bounds__(256) void scan_apply_k(
    bf16* __restrict__ ur, bf16* __restrict__ ui,
    const float* __restrict__ abar,
    const float* __restrict__ car_re, const float* __restrict__ car_im)
{
    int idx = blockIdx.x*256 + threadIdx.x;
    if (idx >= NSCAN) return;
    int p = idx % P_DIM;
    int rest = idx / P_DIM;
    int c = rest % NC, b = rest / NC;
    float ar = abar[p], ai = abar[P_DIM + p];
    size_t co = (size_t)b*NC*P_DIM + (size_t)c*P_DIM + p;
    float xre = car_re[co], xim = car_im[co];
    size_t base = ((size_t)b*LSEQ + (size_t)c*CL)*KP + p;
    for (int i = 0; i < CL; ++i) {
        size_t o = base + (size_t)i*KP;
        float br = __bfloat162float(ur[o]);
        float bi = __bfloat162float(ui[o]);
        float nr = fmaf(ar, xre, fmaf(-ai, xim, br));
        float ni = fmaf(ar, xim, fmaf( ai, xre, bi));
        xre = nr; xim = ni;
        ur[o] = __float2bfloat16(xre);
        ui[o] = __float2bfloat16(xim);
    }
}

// ---------------- head ----------------
__global__ void head_init_k(float* out, const float* hb)
{
    if (threadIdx.x < BSZ) out[threadIdx.x] = hb[0];
}

__global__ __launch_bounds__(256) void head_k(
    const float* __restrict__ h, const float* __restrict__ hw,
    float* __restrict__ out)
{
    int b = blockIdx.x;
    int chunk = blockIdx.y;
    const float* hb = h + ((size_t)b*LSEQ + (size_t)chunk*64)*D_MODEL;
    float s = 0.f;
    for (int l = 0; l < 64; ++l) {
        const float* hr = hb + (size_t)l*D_MODEL;
        for (int d = threadIdx.x; d < D_MODEL; d += 256)
            s += hr[d]*hw[d];
    }
    for (int off = 32; off; off >>= 1) s += __shfl_down(s, off, 64);
    __shared__ float sm[4];
    int lane = threadIdx.x & 63, wv = threadIdx.x >> 6;
    if (lane == 0) sm[wv] = s;
    __syncthreads();
    if (threadIdx.x == 0)
        atomicAdd(out + b, (sm[0]+sm[1]+sm[2]+sm[3]) * (1.f/LSEQ));
}

// ---------------- launch ----------------
extern "C" void kernel_launch(void* const* d_in, const int* in_sizes, int n_in,
                              void* d_out, int out_size, void* d_ws, size_t ws_size,
                              hipStream_t stream)
{
    const float* x          = (const float*)d_in[0];
    const float* enc_w      = (const float*)d_in[1];
    const float* enc_b      = (const float*)d_in[2];
    const float* norm_w     = (const float*)d_in[3];
    const float* norm_b     = (const float*)d_in[4];
    const float* attn_w     = (const float*)d_in[5];
    const float* attn_b     = (const float*)d_in[6];
    const float* ff_w       = (const float*)d_in[7];
    const float* ff_b       = (const float*)d_in[8];
    const float* lam_re     = (const float*)d_in[9];
    const float* lam_im     = (const float*)d_in[10];
    const float* log_step   = (const float*)d_in[11];
    const float* B_re       = (const float*)d_in[12];
    const float* B_im       = (const float*)d_in[13];
    const float* C_re       = (const float*)d_in[14];
    const float* C_im       = (const float*)d_in[15];
    const float* Dvec       = (const float*)d_in[16];
    const float* Wenc       = (const float*)d_in[17];
    const float* Wdec       = (const float*)d_in[18];
    const float* head_w     = (const float*)d_in[19];
    const float* head_b     = (const float*)d_in[20];
    float* out = (float*)d_out;

    // ---- workspace (~233 MB) ----
    float* h    = (float*)d_ws;            // BLD fp32
    bf16*  b1   = (bf16*)(h + BLD);        // BLA bf16 each
    bf16*  b2   = b1 + BLA;
    bf16*  b3   = b2 + BLA;
    bf16*  b4   = b3 + BLA;
    bf16*  wbr  = b4 + BLA;                // Bbar re/im
    bf16*  wbi  = wbr + NPKP;
    bf16*  w5   = wbi + NPKP;              // wcr,wci(-),wea,weg,wd contiguous
    bf16*  wcr  = w5;
    bf16*  wci  = w5 + NPKP;
    bf16*  wea  = w5 + 2*NPKP;
    bf16*  weg  = w5 + 3*NPKP;
    bf16*  wd   = w5 + 4*NPKP;
    float* abar = (float*)(w5 + 5*NPKP);   // 2*P fp32
    float* sum_re = abar + 2*P_DIM;
    float* sum_im = sum_re + NSCAN;
    float* car_re = sum_im + NSCAN;
    float* car_im = car_re + NSCAN;

    const int EW_U = (int)((BLD + 255)/256);
    const int CV   = (int)((NPKP + 255)/256);
    const int SC_G = (NSCAN + 255)/256;
    const size_t pd = (size_t)P_DIM*D_MODEL;

    encode_k<<<EW_U, 256, 0, stream>>>(x, enc_w, enc_b, h);

    for (int i = 0; i < NLAYER; ++i) {
        prep_k<<<CV, 256, 0, stream>>>(
            lam_re + i*P_DIM, lam_im + i*P_DIM, log_step + i*P_DIM,
            B_re + i*pd, B_im + i*pd, wbr, wbi, abar);
        const float* WencA = Wenc + (size_t)i*2*pd;
        const float* WencG = WencA + pd;
        convw5_k<<<dim3(CV,1,5), 256, 0, stream>>>(
            C_re + i*pd, C_im + i*pd, WencA, WencG, Wdec + i*pd, w5);

        // fx = LN(LN(h)) in one pass
        ln2x_k<<<BL, 256, 0, stream>>>(h, norm_w + i*D_MODEL, norm_b + i*D_MODEL,
                                       attn_w + i*D_MODEL, attn_b + i*D_MODEL, b2);

        // Bu_re, Bu_im in one dual-output GEMM
        gemm2o_k<0><<<NGEMM, 256, 0, stream>>>(b2, wbr, wbi, b1, b3, P_DIM);

        // chunked parallel scan (in-place on b1/b3)
        scan_partial_k<<<SC_G, 256, 0, stream>>>(b1, b3, abar, sum_re, sum_im);
        scan_carry_k<<<(BSZ*P_DIM + 255)/256, 256, 0, stream>>>(sum_re, sum_im, abar, car_re, car_im);
        scan_apply_k<<<SC_G, 256, 0, stream>>>(b1, b3, abar, car_re, car_im);

        // z2 = gelu(xs_re@C_re^T + xs_im@(-C_im)^T + Dvec*fx) + fx
        gemmC_k<<<NGEMM, 256, 0, stream>>>(b1, wcr, b3, wci, b2, Dvec + i*D_MODEL, b4, D_MODEL);

        // fy = LN(z2)
        ln_k<<<BL, 256, 0, stream>>>(b4, ff_w + i*D_MODEL, ff_b + i*D_MODEL, b1);

        // GEGLU MLP: b2 = (fy@WencA^T) * gelu(fy@WencG^T)
        gemm2o_k<1><<<NGEMM, 256, 0, stream>>>(b1, wea, weg, b2, nullptr, D_MODEL);

        // h += b2@Wdec^T + fy
        gemmD_k<<<NGEMM, 256, 0, stream>>>(b2, wd, b1, h, D_MODEL);
    }

    head_init_k<<<1, 64, 0, stream>>>(out, head_b);
    head_k<<<dim3(BSZ, 64), 256, 0, stream>>>(h, head_w, out);
}